// Round 1
// baseline (1721.066 us; speedup 1.0000x reference)
//
#include <hip/hip_runtime.h>
#include <cstdint>
#include <cstddef>

#define N_NODES 100000
#define N_EDGES 1200000
#define ASIZE 256
#define HSIZE 64
#define NTYPES 4
#define NSTEPS 6
#define NGRAPH 64
#define PS 16   // pooling splits per graph

static __device__ __forceinline__ float sigmoidf_(float x) { return 1.0f / (1.0f + expf(-x)); }

// ---------------- CSR build (by dst) ----------------
__global__ void k_count(const int* __restrict__ dst, int* __restrict__ deg) {
    int e = blockIdx.x * 256 + threadIdx.x;
    if (e < N_EDGES) atomicAdd(&deg[dst[e]], 1);
}

__global__ void k_scan1(const int* __restrict__ deg, int* __restrict__ rs, int* __restrict__ part) {
    __shared__ int sh[256];
    int t = threadIdx.x;
    int base = blockIdx.x * 1024 + t * 4;
    int v0 = (base + 0 < N_NODES) ? deg[base + 0] : 0;
    int v1 = (base + 1 < N_NODES) ? deg[base + 1] : 0;
    int v2 = (base + 2 < N_NODES) ? deg[base + 2] : 0;
    int v3 = (base + 3 < N_NODES) ? deg[base + 3] : 0;
    int s = v0 + v1 + v2 + v3;
    sh[t] = s;
    __syncthreads();
    for (int off = 1; off < 256; off <<= 1) {
        int x = (t >= off) ? sh[t - off] : 0;
        __syncthreads();
        sh[t] += x;
        __syncthreads();
    }
    int excl = sh[t] - s;
    if (t == 255) part[blockIdx.x] = sh[255];
    if (base + 0 < N_NODES) rs[base + 0] = excl;
    if (base + 1 < N_NODES) rs[base + 1] = excl + v0;
    if (base + 2 < N_NODES) rs[base + 2] = excl + v0 + v1;
    if (base + 3 < N_NODES) rs[base + 3] = excl + v0 + v1 + v2;
}

__global__ void k_scan2(int* __restrict__ part, int* __restrict__ rs, int nb) {
    if (threadIdx.x == 0 && blockIdx.x == 0) {
        int run = 0;
        for (int i = 0; i < nb; ++i) { int v = part[i]; part[i] = run; run += v; }
        rs[N_NODES] = run;
    }
}

__global__ void k_scan3(int* __restrict__ rs, const int* __restrict__ part) {
    int i = blockIdx.x * 256 + threadIdx.x;
    if (i < N_NODES) rs[i] += part[i >> 10];
}

// colidx holds a precomputed float-offset into buf1: src*448 + 192 + ety*64
__global__ void k_fill(const int* __restrict__ src, const int* __restrict__ dst,
                       const int* __restrict__ ety, const int* __restrict__ rs,
                       int* __restrict__ cur, int* __restrict__ colidx) {
    int e = blockIdx.x * 256 + threadIdx.x;
    if (e < N_EDGES) {
        int d = dst[e];
        int pos = rs[d] + atomicAdd(&cur[d], 1);
        colidx[pos] = src[e] * 448 + 192 + ety[e] * 64;
    }
}

// ---------------- weight prep ----------------
__global__ void k_prep2(const float* __restrict__ Wh, const float* __restrict__ Bh,
                        const float* __restrict__ eW, const float* __restrict__ eb,
                        const float* __restrict__ Wi, const float* __restrict__ Bi,
                        float* __restrict__ W448, float* __restrict__ bias448,
                        float* __restrict__ WiA, float* __restrict__ biA) {
    int idx = blockIdx.x * 256 + threadIdx.x;
    if (idx < 64 * 448) {
        int k = idx / 448, m = idx % 448;
        float v;
        if (m < 192) {
            int j = m / 3, g = m % 3;
            v = Wh[(g * 64 + j) * 64 + k];
        } else {
            v = eW[(size_t)(m - 192 >> 6) * 4096 + k * 64 + ((m - 192) & 63)];
        }
        W448[idx] = v;
    }
    if (idx < 64 * 192) {
        int k = idx / 192, m = idx % 192;
        int j = m / 3, g = m % 3;
        WiA[idx] = Wi[(g * 64 + j) * 64 + k];
    }
    if (idx < 448) {
        bias448[idx] = (idx < 192) ? Bh[(idx % 3) * 64 + idx / 3] : eb[idx - 192];
    }
    if (idx < 192) {
        biA[idx] = Bi[(idx % 3) * 64 + idx / 3];
    }
}

// ---------------- step GEMM: buf1[N][448] = h[N][64] @ W448[64][448] + bias448 ----------------
// grid = ntiles (128-node tiles). X staged ONCE; loop 7 mtiles in-block with
// register-prefetch of next W tile (issue-early / write-late): W(m+1) global loads
// issue before compute of mtile m, land in LDS between two barriers after compute.
// Output stores placed after the barrier pair so they drain under the next mtile's compute.
// FP order per output identical to the previous k_gemm (bit-exact).
__global__ __launch_bounds__(256) void k_gemm_step(const float* __restrict__ X,
                                                   const float* __restrict__ W,
                                                   const float* __restrict__ bias,
                                                   float* __restrict__ Y) {
    __shared__ float sX[128 * 66];
    __shared__ float sW[64 * 64];
    int tid = threadIdx.x;
    int ntile = blockIdx.x * 128;
    int tc4 = (tid & 15) * 4;
    int tr = tid >> 4;
    int swr = tid >> 4;          // W-stage row within 16-row group
    int swc = (tid & 15) * 4;    // W-stage col

    // stage X tile [128 nodes][64 k] once (padded stride 66)
#pragma unroll
    for (int i = 0; i < 8; ++i) {
        int lin4 = (i * 256 + tid) * 4;
        int nl = lin4 >> 6, kk = lin4 & 63;
        int n = ntile + nl;
        float4 v = make_float4(0.f, 0.f, 0.f, 0.f);
        if (n < N_NODES) v = *(const float4*)(X + (size_t)n * 64 + kk);
        float* d = sX + nl * 66 + kk;
        d[0] = v.x; d[1] = v.y; d[2] = v.z; d[3] = v.w;
    }
    // stage W tile 0
    float4 wreg[4];
#pragma unroll
    for (int i = 0; i < 4; ++i)
        wreg[i] = *(const float4*)(W + (size_t)(i * 16 + swr) * 448 + swc);
#pragma unroll
    for (int i = 0; i < 4; ++i)
        *(float4*)(sW + (i * 16 + swr) * 64 + swc) = wreg[i];
    __syncthreads();

    const float* xr = sX + tr * 8 * 66;
    const float* wrp = sW + tc4;
    for (int m = 0; m < 7; ++m) {
        // prefetch next W tile into registers (completes during compute below)
        if (m < 6) {
#pragma unroll
            for (int i = 0; i < 4; ++i)
                wreg[i] = *(const float4*)(W + (size_t)(i * 16 + swr) * 448 + (m + 1) * 64 + swc);
        }
        float4 acc[8];
#pragma unroll
        for (int i = 0; i < 8; ++i) acc[i] = make_float4(0.f, 0.f, 0.f, 0.f);
        for (int kk = 0; kk < 64; kk += 2) {
            float4 wA = *(const float4*)(wrp + kk * 64);
            float4 wB = *(const float4*)(wrp + (kk + 1) * 64);
            float xA[8], xB[8];
#pragma unroll
            for (int i = 0; i < 8; ++i) { xA[i] = xr[i * 66 + kk]; xB[i] = xr[i * 66 + kk + 1]; }
#pragma unroll
            for (int i = 0; i < 8; ++i) {
                acc[i].x = fmaf(xA[i], wA.x, acc[i].x);
                acc[i].y = fmaf(xA[i], wA.y, acc[i].y);
                acc[i].z = fmaf(xA[i], wA.z, acc[i].z);
                acc[i].w = fmaf(xA[i], wA.w, acc[i].w);
            }
#pragma unroll
            for (int i = 0; i < 8; ++i) {
                acc[i].x = fmaf(xB[i], wB.x, acc[i].x);
                acc[i].y = fmaf(xB[i], wB.y, acc[i].y);
                acc[i].z = fmaf(xB[i], wB.z, acc[i].z);
                acc[i].w = fmaf(xB[i], wB.w, acc[i].w);
            }
        }
        float4 bv = *(const float4*)(bias + m * 64 + tc4);
        // commit prefetched W to LDS (B1: all readers of sW done; B2: writes visible)
        if (m < 6) {
            __syncthreads();
#pragma unroll
            for (int i = 0; i < 4; ++i)
                *(float4*)(sW + (i * 16 + swr) * 64 + swc) = wreg[i];
            __syncthreads();
        }
        // stores AFTER the barrier pair: they drain under the next mtile's compute
#pragma unroll
        for (int i = 0; i < 8; ++i) {
            int n = ntile + tr * 8 + i;
            if (n < N_NODES) {
                float4 y;
                y.x = acc[i].x + bv.x; y.y = acc[i].y + bv.y;
                y.z = acc[i].z + bv.z; y.w = acc[i].w + bv.w;
                *(float4*)(Y + (size_t)n * 448 + m * 64 + tc4) = y;
            }
        }
    }
}

// ---------------- reduce GEMM: h = h0 = ann[N][256] @ rW[256][64] + rb ----------------
// K pipelined: next X/W chunk prefetched into registers while computing the current
// chunk from LDS (single-buffered, 2 barriers per chunk). FP order identical to before.
__global__ __launch_bounds__(256) void k_gemm_red(const float* __restrict__ X,
                                                  const float* __restrict__ W,
                                                  const float* __restrict__ bias,
                                                  float* __restrict__ Y,
                                                  float* __restrict__ Y2) {
    __shared__ float sX[128 * 66];
    __shared__ float sW[64 * 64];
    int tid = threadIdx.x;
    int ntile = blockIdx.x * 128;
    int tc4 = (tid & 15) * 4;
    int tr = tid >> 4;
    int swr = tid >> 4;
    int swc = (tid & 15) * 4;

    float4 acc[8];
#pragma unroll
    for (int i = 0; i < 8; ++i) acc[i] = make_float4(0.f, 0.f, 0.f, 0.f);

    float4 xreg[8];
    float4 wreg[4];
    // prefetch chunk 0
#pragma unroll
    for (int i = 0; i < 8; ++i) {
        int lin4 = (i * 256 + tid) * 4;
        int nl = lin4 >> 6, kk = lin4 & 63;
        int n = ntile + nl;
        float4 v = make_float4(0.f, 0.f, 0.f, 0.f);
        if (n < N_NODES) v = *(const float4*)(X + (size_t)n * 256 + kk);
        xreg[i] = v;
    }
#pragma unroll
    for (int i = 0; i < 4; ++i)
        wreg[i] = *(const float4*)(W + (size_t)(i * 16 + swr) * 64 + swc);

    for (int kc = 0; kc < 4; ++kc) {
        // commit staged chunk to LDS
#pragma unroll
        for (int i = 0; i < 8; ++i) {
            int lin4 = (i * 256 + tid) * 4;
            int nl = lin4 >> 6, kk = lin4 & 63;
            float* d = sX + nl * 66 + kk;
            d[0] = xreg[i].x; d[1] = xreg[i].y; d[2] = xreg[i].z; d[3] = xreg[i].w;
        }
#pragma unroll
        for (int i = 0; i < 4; ++i)
            *(float4*)(sW + (i * 16 + swr) * 64 + swc) = wreg[i];
        __syncthreads();
        // prefetch next chunk into registers; completes during compute below
        if (kc < 3) {
#pragma unroll
            for (int i = 0; i < 8; ++i) {
                int lin4 = (i * 256 + tid) * 4;
                int nl = lin4 >> 6, kk = lin4 & 63;
                int n = ntile + nl;
                float4 v = make_float4(0.f, 0.f, 0.f, 0.f);
                if (n < N_NODES) v = *(const float4*)(X + (size_t)n * 256 + (kc + 1) * 64 + kk);
                xreg[i] = v;
            }
#pragma unroll
            for (int i = 0; i < 4; ++i)
                wreg[i] = *(const float4*)(W + (size_t)((kc + 1) * 64 + i * 16 + swr) * 64 + swc);
        }
        // compute current chunk
        const float* xr = sX + tr * 8 * 66;
        const float* wrp = sW + tc4;
        for (int kk = 0; kk < 64; kk += 2) {
            float4 wA = *(const float4*)(wrp + kk * 64);
            float4 wB = *(const float4*)(wrp + (kk + 1) * 64);
            float xA[8], xB[8];
#pragma unroll
            for (int i = 0; i < 8; ++i) { xA[i] = xr[i * 66 + kk]; xB[i] = xr[i * 66 + kk + 1]; }
#pragma unroll
            for (int i = 0; i < 8; ++i) {
                acc[i].x = fmaf(xA[i], wA.x, acc[i].x);
                acc[i].y = fmaf(xA[i], wA.y, acc[i].y);
                acc[i].z = fmaf(xA[i], wA.z, acc[i].z);
                acc[i].w = fmaf(xA[i], wA.w, acc[i].w);
            }
#pragma unroll
            for (int i = 0; i < 8; ++i) {
                acc[i].x = fmaf(xB[i], wB.x, acc[i].x);
                acc[i].y = fmaf(xB[i], wB.y, acc[i].y);
                acc[i].z = fmaf(xB[i], wB.z, acc[i].z);
                acc[i].w = fmaf(xB[i], wB.w, acc[i].w);
            }
        }
        if (kc < 3) __syncthreads();  // readers done before next commit
    }
    float4 bv = *(const float4*)(bias + tc4);
#pragma unroll
    for (int i = 0; i < 8; ++i) {
        int n = ntile + tr * 8 + i;
        if (n < N_NODES) {
            float4 y;
            y.x = acc[i].x + bv.x; y.y = acc[i].y + bv.y;
            y.z = acc[i].z + bv.z; y.w = acc[i].w + bv.w;
            *(float4*)(Y + (size_t)n * 64 + tc4) = y;
            *(float4*)(Y2 + (size_t)n * 64 + tc4) = y;
        }
    }
}

// ---------------- edge aggregate: a[n] = sum of incoming trans rows from buf1 ----------------
__global__ void k_aggregate(const float* __restrict__ buf1, const int* __restrict__ rs,
                            const int* __restrict__ colidx, float* __restrict__ a) {
    int l = threadIdx.x & 63;
    int n = blockIdx.x * 4 + (threadIdx.x >> 6);  // 25000 blocks * 4 = N exactly
    int beg = rs[n], end = rs[n + 1];             // wave-uniform
    float a0 = 0.f, a1 = 0.f, a2 = 0.f, a3 = 0.f;
    int s = beg;
    for (; s + 3 < end; s += 4) {
        int c0 = colidx[s], c1 = colidx[s + 1], c2 = colidx[s + 2], c3 = colidx[s + 3];
        a0 += buf1[(size_t)c0 + l];
        a1 += buf1[(size_t)c1 + l];
        a2 += buf1[(size_t)c2 + l];
        a3 += buf1[(size_t)c3 + l];
    }
    for (; s < end; ++s) a0 += buf1[(size_t)colidx[s] + l];
    a[(size_t)n * 64 + l] = (a0 + a1) + (a2 + a3);
}

// ---------------- fused gi-GEMM + GRU gate epilogue ----------------
__global__ __launch_bounds__(256) void k_gruF(const float* __restrict__ A,
                                              const float* __restrict__ WiA,
                                              const float* __restrict__ biA,
                                              const float* __restrict__ buf1,
                                              float* __restrict__ H) {
    __shared__ float sX[64 * 34];
    __shared__ float sW[32 * 192];
    int tid = threadIdx.x;
    int ntile = blockIdx.x * 64;
    int tc = tid & 15;
    int tr = tid >> 4;
    float acc[4][12];
#pragma unroll
    for (int i = 0; i < 4; ++i)
#pragma unroll
        for (int c = 0; c < 12; ++c) acc[i][c] = 0.f;

    for (int kc = 0; kc < 2; ++kc) {
        if (kc) __syncthreads();
#pragma unroll
        for (int i = 0; i < 2; ++i) {
            int lin4 = (i * 256 + tid) * 4;
            int nl = lin4 >> 5, kk = lin4 & 31;
            int n = ntile + nl;
            float4 v = make_float4(0.f, 0.f, 0.f, 0.f);
            if (n < N_NODES) v = *(const float4*)(A + (size_t)n * 64 + kc * 32 + kk);
            float* d = sX + nl * 34 + kk;
            d[0] = v.x; d[1] = v.y; d[2] = v.z; d[3] = v.w;
        }
        {
            int kk = tid >> 3, c = (tid & 7) * 24;
            const float* srcp = WiA + (size_t)(kc * 32 + kk) * 192 + c;
            float* d = sW + kk * 192 + c;
#pragma unroll
            for (int u = 0; u < 6; ++u) *(float4*)(d + 4 * u) = *(const float4*)(srcp + 4 * u);
        }
        __syncthreads();
        const float* xr = sX + tr * 4 * 34;
        const float* wr = sW + tc * 12;
        for (int kk = 0; kk < 32; kk += 2) {
            float4 w0 = *(const float4*)(wr + kk * 192);
            float4 w1 = *(const float4*)(wr + kk * 192 + 4);
            float4 w2 = *(const float4*)(wr + kk * 192 + 8);
            float4 u0 = *(const float4*)(wr + (kk + 1) * 192);
            float4 u1 = *(const float4*)(wr + (kk + 1) * 192 + 4);
            float4 u2 = *(const float4*)(wr + (kk + 1) * 192 + 8);
            float xA[4], xB[4];
#pragma unroll
            for (int i = 0; i < 4; ++i) { xA[i] = xr[i * 34 + kk]; xB[i] = xr[i * 34 + kk + 1]; }
#pragma unroll
            for (int i = 0; i < 4; ++i) {
                acc[i][0]  = fmaf(xA[i], w0.x, acc[i][0]);
                acc[i][1]  = fmaf(xA[i], w0.y, acc[i][1]);
                acc[i][2]  = fmaf(xA[i], w0.z, acc[i][2]);
                acc[i][3]  = fmaf(xA[i], w0.w, acc[i][3]);
                acc[i][4]  = fmaf(xA[i], w1.x, acc[i][4]);
                acc[i][5]  = fmaf(xA[i], w1.y, acc[i][5]);
                acc[i][6]  = fmaf(xA[i], w1.z, acc[i][6]);
                acc[i][7]  = fmaf(xA[i], w1.w, acc[i][7]);
                acc[i][8]  = fmaf(xA[i], w2.x, acc[i][8]);
                acc[i][9]  = fmaf(xA[i], w2.y, acc[i][9]);
                acc[i][10] = fmaf(xA[i], w2.z, acc[i][10]);
                acc[i][11] = fmaf(xA[i], w2.w, acc[i][11]);
            }
#pragma unroll
            for (int i = 0; i < 4; ++i) {
                acc[i][0]  = fmaf(xB[i], u0.x, acc[i][0]);
                acc[i][1]  = fmaf(xB[i], u0.y, acc[i][1]);
                acc[i][2]  = fmaf(xB[i], u0.z, acc[i][2]);
                acc[i][3]  = fmaf(xB[i], u0.w, acc[i][3]);
                acc[i][4]  = fmaf(xB[i], u1.x, acc[i][4]);
                acc[i][5]  = fmaf(xB[i], u1.y, acc[i][5]);
                acc[i][6]  = fmaf(xB[i], u1.z, acc[i][6]);
                acc[i][7]  = fmaf(xB[i], u1.w, acc[i][7]);
                acc[i][8]  = fmaf(xB[i], u2.x, acc[i][8]);
                acc[i][9]  = fmaf(xB[i], u2.y, acc[i][9]);
                acc[i][10] = fmaf(xB[i], u2.z, acc[i][10]);
                acc[i][11] = fmaf(xB[i], u2.w, acc[i][11]);
            }
        }
    }
    float bb[12];
    {
        float4 b0 = *(const float4*)(biA + tc * 12);
        float4 b1 = *(const float4*)(biA + tc * 12 + 4);
        float4 b2 = *(const float4*)(biA + tc * 12 + 8);
        bb[0] = b0.x; bb[1] = b0.y; bb[2] = b0.z; bb[3] = b0.w;
        bb[4] = b1.x; bb[5] = b1.y; bb[6] = b1.z; bb[7] = b1.w;
        bb[8] = b2.x; bb[9] = b2.y; bb[10] = b2.z; bb[11] = b2.w;
    }
#pragma unroll
    for (int i = 0; i < 4; ++i) {
        int n = ntile + tr * 4 + i;
        if (n >= N_NODES) continue;
        const float* ghp = buf1 + (size_t)n * 448 + tc * 12;
        float gg[12];
        float4 g0 = *(const float4*)(ghp);
        float4 g1 = *(const float4*)(ghp + 4);
        float4 g2 = *(const float4*)(ghp + 8);
        gg[0] = g0.x; gg[1] = g0.y; gg[2] = g0.z; gg[3] = g0.w;
        gg[4] = g1.x; gg[5] = g1.y; gg[6] = g1.z; gg[7] = g1.w;
        gg[8] = g2.x; gg[9] = g2.y; gg[10] = g2.z; gg[11] = g2.w;
        float4 hv = *(const float4*)(H + (size_t)n * 64 + tc * 4);
        float res[4];
#pragma unroll
        for (int jj = 0; jj < 4; ++jj) {
            int c = jj * 3;
            float r = sigmoidf_(acc[i][c] + bb[c] + gg[c]);
            float z = sigmoidf_(acc[i][c + 1] + bb[c + 1] + gg[c + 1]);
            float nn = tanhf(acc[i][c + 2] + bb[c + 2] + r * gg[c + 2]);
            float hj = (jj == 0) ? hv.x : (jj == 1) ? hv.y : (jj == 2) ? hv.z : hv.w;
            res[jj] = (1.f - z) * nn + z * hj;
        }
        float4 o; o.x = res[0]; o.y = res[1]; o.z = res[2]; o.w = res[3];
        *(float4*)(H + (size_t)n * 64 + tc * 4) = o;
    }
}

// ---------------- pooling: segmented, atomic-free, multi-block per graph ----------------
__global__ void k_bounds(const int* __restrict__ gid, int* __restrict__ start) {
    int n = blockIdx.x * 256 + threadIdx.x;
    if (n < N_NODES) {
        int g = gid[n];
        if (n == 0) {
            for (int x = 0; x <= g; ++x) start[x] = 0;
        } else {
            int pg = gid[n - 1];
            for (int x = pg + 1; x <= g; ++x) start[x] = n;
        }
        if (n == N_NODES - 1) {
            for (int x = g + 1; x <= NGRAPH; ++x) start[x] = N_NODES;
        }
    }
}

__global__ void k_gate2(const float* __restrict__ H, const float* __restrict__ H0,
                        const float* __restrict__ gW, const float* __restrict__ gb,
                        float* __restrict__ gate) {
    int l = threadIdx.x & 63;
    int n = blockIdx.x * 4 + (threadIdx.x >> 6);
    float v = H[(size_t)n * 64 + l] * gW[l] + H0[(size_t)n * 64 + l] * gW[64 + l];
    for (int off = 32; off > 0; off >>= 1) v += __shfl_xor(v, off, 64);
    if (l == 0) gate[n] = v + gb[0];
}

__global__ __launch_bounds__(64) void k_poolA(const float* __restrict__ gate,
                                              const int* __restrict__ start,
                                              float* __restrict__ pmax) {
    int g = blockIdx.x, s = blockIdx.y;
    int beg = start[g], len = start[g + 1] - beg;
    int sb = beg + (int)((long long)len * s / PS);
    int se = beg + (int)((long long)len * (s + 1) / PS);
    float m = -INFINITY;
    for (int n = sb + threadIdx.x; n < se; n += 64) m = fmaxf(m, gate[n]);
    for (int off = 32; off > 0; off >>= 1) m = fmaxf(m, __shfl_xor(m, off, 64));
    if (threadIdx.x == 0) pmax[g * PS + s] = m;
}

__global__ void k_poolB(const float* __restrict__ pmax, float* __restrict__ gm) {
    int g = threadIdx.x;  // 64 threads
    float m = -INFINITY;
    for (int s = 0; s < PS; ++s) m = fmaxf(m, pmax[g * PS + s]);
    if (!isfinite(m)) m = 0.0f;   // reference's empty-graph guard
    gm[g] = m;
}

__global__ __launch_bounds__(256) void k_poolC(const float* __restrict__ H,
                                               const float* __restrict__ H0,
                                               const float* __restrict__ gate,
                                               const int* __restrict__ start,
                                               const float* __restrict__ gm,
                                               float* __restrict__ pnum,
                                               float* __restrict__ pden) {
    int g = blockIdx.x, s = blockIdx.y;
    int beg = start[g], len = start[g + 1] - beg;
    int sb = beg + (int)((long long)len * s / PS);
    int se = beg + (int)((long long)len * (s + 1) / PS);
    int t = threadIdx.x;
    int lane = t & 63, wave = t >> 6;
    float m = gm[g];
    __shared__ float shh[4][64], sh0[4][64], ses[4];
    float ah = 0.f, ah0 = 0.f, es = 0.f;
    for (int n = sb + wave; n < se; n += 4) {
        float e = expf(gate[n] - m);
        es += e;
        ah  += e * H [(size_t)n * 64 + lane];
        ah0 += e * H0[(size_t)n * 64 + lane];
    }
    shh[wave][lane] = ah; sh0[wave][lane] = ah0;
    if (lane == 0) ses[wave] = es;
    __syncthreads();
    if (wave == 0) {
        float r  = shh[0][lane] + shh[1][lane] + shh[2][lane] + shh[3][lane];
        float r0 = sh0[0][lane] + sh0[1][lane] + sh0[2][lane] + sh0[3][lane];
        int base = (g * PS + s) * 128;
        pnum[base + lane]      = r;
        pnum[base + 64 + lane] = r0;
        if (lane == 0) pden[g * PS + s] = ses[0] + ses[1] + ses[2] + ses[3];
    }
}

__global__ __launch_bounds__(128) void k_poolD(const float* __restrict__ pnum,
                                               const float* __restrict__ pden,
                                               float* __restrict__ ro) {
    int g = blockIdx.x;
    int c = threadIdx.x;
    float den = 0.f;
    for (int s = 0; s < PS; ++s) den += pden[g * PS + s];
    float nu = 0.f;
    for (int s = 0; s < PS; ++s) nu += pnum[(g * PS + s) * 128 + c];
    ro[g * 128 + c] = (den > 0.f) ? nu / den : 0.f;
}

__global__ void k_logits(const float* __restrict__ ro, const float* __restrict__ oW,
                         const float* __restrict__ ob, float* __restrict__ out) {
    int t = threadIdx.x;
    int b = t >> 1;
    int c = t & 1;
    float acc = ob[c];
    for (int k = 0; k < 128; ++k) acc = fmaf(ro[b * 128 + k], oW[k * 2 + c], acc);
    out[b * 2 + c] = acc;
}

extern "C" void kernel_launch(void* const* d_in, const int* in_sizes, int n_in,
                              void* d_out, int out_size, void* d_ws, size_t ws_size,
                              hipStream_t stream) {
    (void)in_sizes; (void)n_in; (void)out_size; (void)ws_size;
    const float* ann = (const float*)d_in[0];
    const int* src   = (const int*)d_in[1];
    const int* dst   = (const int*)d_in[2];
    const int* ety   = (const int*)d_in[3];
    const int* gid   = (const int*)d_in[4];
    const float* rW  = (const float*)d_in[5];
    const float* rb  = (const float*)d_in[6];
    const float* eW  = (const float*)d_in[7];
    const float* eb  = (const float*)d_in[8];
    const float* Wi  = (const float*)d_in[9];
    const float* Bi  = (const float*)d_in[10];
    const float* Wh  = (const float*)d_in[11];
    const float* Bh  = (const float*)d_in[12];
    const float* gW  = (const float*)d_in[13];
    const float* gb  = (const float*)d_in[14];
    const float* oW  = (const float*)d_in[15];
    const float* ob  = (const float*)d_in[16];
    float* out = (float*)d_out;

    char* p = (char*)d_ws;
    auto take = [&](size_t nbytes) -> void* {
        void* r = (void*)p;
        p += (nbytes + 255) & ~((size_t)255);
        return r;
    };
    float* h0      = (float*)take((size_t)N_NODES * 64 * 4);
    float* h       = (float*)take((size_t)N_NODES * 64 * 4);
    float* abuf    = (float*)take((size_t)N_NODES * 64 * 4);
    float* buf1    = (float*)take((size_t)N_NODES * 448 * 4);   // [gh(192, j*3+g) | trans(4x64)]
    float* W448    = (float*)take(64 * 448 * 4);
    float* bias448 = (float*)take(448 * 4);
    float* WiA     = (float*)take(64 * 192 * 4);
    float* biA     = (float*)take(192 * 4);
    int* deg       = (int*)take((size_t)N_NODES * 4);
    int* cur       = (int*)take((size_t)N_NODES * 4);
    int* rs        = (int*)take((size_t)(N_NODES + 1) * 4);
    int* part      = (int*)take(512);
    int* colidx    = (int*)take((size_t)N_EDGES * 4);
    float* gate    = (float*)take((size_t)N_NODES * 4);
    int* start     = (int*)take((size_t)(NGRAPH + 1) * 4);
    float* pmax    = (float*)take(NGRAPH * PS * 4);
    float* gm      = (float*)take(NGRAPH * 4);
    float* pnum    = (float*)take((size_t)NGRAPH * PS * 128 * 4);
    float* pden    = (float*)take(NGRAPH * PS * 4);
    float* ro      = (float*)take(NGRAPH * 128 * 4);

    // ---- CSR build (by dst)
    hipMemsetAsync(deg, 0, (size_t)N_NODES * 4, stream);
    hipMemsetAsync(cur, 0, (size_t)N_NODES * 4, stream);
    k_count<<<(N_EDGES + 255) / 256, 256, 0, stream>>>(dst, deg);
    int nb = (N_NODES + 1023) / 1024;  // 98
    k_scan1<<<nb, 256, 0, stream>>>(deg, rs, part);
    k_scan2<<<1, 64, 0, stream>>>(part, rs, nb);
    k_scan3<<<(N_NODES + 255) / 256, 256, 0, stream>>>(rs, part);
    k_fill<<<(N_EDGES + 255) / 256, 256, 0, stream>>>(src, dst, ety, rs, cur, colidx);

    // ---- weight prep + graph bounds
    k_prep2<<<112, 256, 0, stream>>>(Wh, Bh, eW, eb, Wi, Bi, W448, bias448, WiA, biA);
    k_bounds<<<(N_NODES + 255) / 256, 256, 0, stream>>>(gid, start);

    int ntiles = (N_NODES + 127) / 128;  // 782

    // ---- reduce layer: h = h0 = ann @ rW + rb (K-pipelined)
    k_gemm_red<<<ntiles, 256, 0, stream>>>(ann, rW, rb, h, h0);

    // ---- message-passing steps (X staged once per tile; 7 mtiles looped in-block)
    for (int s = 0; s < NSTEPS; ++s) {
        k_gemm_step<<<ntiles, 256, 0, stream>>>(h, W448, bias448, buf1);
        k_aggregate<<<N_NODES / 4, 256, 0, stream>>>(buf1, rs, colidx, abuf);
        k_gruF<<<(N_NODES + 63) / 64, 256, 0, stream>>>(abuf, WiA, biA, buf1, h);
    }

    // ---- pooling + classifier (atomic-free, multi-block)
    k_gate2<<<N_NODES / 4, 256, 0, stream>>>(h, h0, gW, gb, gate);
    k_poolA<<<dim3(NGRAPH, PS), 64, 0, stream>>>(gate, start, pmax);
    k_poolB<<<1, 64, 0, stream>>>(pmax, gm);
    k_poolC<<<dim3(NGRAPH, PS), 256, 0, stream>>>(h, h0, gate, start, gm, pnum, pden);
    k_poolD<<<NGRAPH, 128, 0, stream>>>(pnum, pden, ro);
    k_logits<<<1, 128, 0, stream>>>(ro, oW, ob, out);
}

// Round 2
// 1566.795 us; speedup vs baseline: 1.0985x; 1.0985x over previous
//
#include <hip/hip_runtime.h>
#include <cstdint>
#include <cstddef>

#define N_NODES 100000
#define N_EDGES 1200000
#define ASIZE 256
#define HSIZE 64
#define NTYPES 4
#define NSTEPS 6
#define NGRAPH 64
#define PS 16   // pooling splits per graph

static __device__ __forceinline__ float sigmoidf_(float x) { return 1.0f / (1.0f + expf(-x)); }

// ---------------- CSR build (by dst) ----------------
__global__ void k_count(const int* __restrict__ dst, int* __restrict__ deg) {
    int e = blockIdx.x * 256 + threadIdx.x;
    if (e < N_EDGES) atomicAdd(&deg[dst[e]], 1);
}

__global__ void k_scan1(const int* __restrict__ deg, int* __restrict__ rs, int* __restrict__ part) {
    __shared__ int sh[256];
    int t = threadIdx.x;
    int base = blockIdx.x * 1024 + t * 4;
    int v0 = (base + 0 < N_NODES) ? deg[base + 0] : 0;
    int v1 = (base + 1 < N_NODES) ? deg[base + 1] : 0;
    int v2 = (base + 2 < N_NODES) ? deg[base + 2] : 0;
    int v3 = (base + 3 < N_NODES) ? deg[base + 3] : 0;
    int s = v0 + v1 + v2 + v3;
    sh[t] = s;
    __syncthreads();
    for (int off = 1; off < 256; off <<= 1) {
        int x = (t >= off) ? sh[t - off] : 0;
        __syncthreads();
        sh[t] += x;
        __syncthreads();
    }
    int excl = sh[t] - s;
    if (t == 255) part[blockIdx.x] = sh[255];
    if (base + 0 < N_NODES) rs[base + 0] = excl;
    if (base + 1 < N_NODES) rs[base + 1] = excl + v0;
    if (base + 2 < N_NODES) rs[base + 2] = excl + v0 + v1;
    if (base + 3 < N_NODES) rs[base + 3] = excl + v0 + v1 + v2;
}

__global__ void k_scan2(int* __restrict__ part, int* __restrict__ rs, int nb) {
    if (threadIdx.x == 0 && blockIdx.x == 0) {
        int run = 0;
        for (int i = 0; i < nb; ++i) { int v = part[i]; part[i] = run; run += v; }
        rs[N_NODES] = run;
    }
}

__global__ void k_scan3(int* __restrict__ rs, const int* __restrict__ part) {
    int i = blockIdx.x * 256 + threadIdx.x;
    if (i < N_NODES) rs[i] += part[i >> 10];
}

// colidx holds a precomputed float-offset into buf1 (now [N][256] trans-only): src*256 + ety*64
__global__ void k_fill(const int* __restrict__ src, const int* __restrict__ dst,
                       const int* __restrict__ ety, const int* __restrict__ rs,
                       int* __restrict__ cur, int* __restrict__ colidx) {
    int e = blockIdx.x * 256 + threadIdx.x;
    if (e < N_EDGES) {
        int d = dst[e];
        int pos = rs[d] + atomicAdd(&cur[d], 1);
        colidx[pos] = src[e] * 256 + ety[e] * 64;
    }
}

// ---------------- weight prep ----------------
// W256[k][c]: c = t*64+jj -> eW[t][k][jj]; b256[c] = eb[c]
// Wh192[k][m]: m = j*3+g -> Wh[(g*64+j)][k]; bh192[m] = Bh[g*64+j]
// WiA[k][j*3+g] = Wi[(g*64+j)][k]; biA[j*3+g] = Bi[g*64+j]
__global__ void k_prep2(const float* __restrict__ Wh, const float* __restrict__ Bh,
                        const float* __restrict__ eW, const float* __restrict__ eb,
                        const float* __restrict__ Wi, const float* __restrict__ Bi,
                        float* __restrict__ W256, float* __restrict__ b256,
                        float* __restrict__ Wh192, float* __restrict__ bh192,
                        float* __restrict__ WiA, float* __restrict__ biA) {
    int idx = blockIdx.x * 256 + threadIdx.x;
    if (idx < 64 * 256) {
        int k = idx / 256, c = idx % 256;
        W256[idx] = eW[(size_t)(c >> 6) * 4096 + k * 64 + (c & 63)];
    }
    if (idx < 64 * 192) {
        int k = idx / 192, m = idx % 192;
        int j = m / 3, g = m % 3;
        WiA[idx]   = Wi[(g * 64 + j) * 64 + k];
        Wh192[idx] = Wh[(g * 64 + j) * 64 + k];
    }
    if (idx < 256) b256[idx] = eb[idx];
    if (idx < 192) {
        biA[idx]   = Bi[(idx % 3) * 64 + idx / 3];
        bh192[idx] = Bh[(idx % 3) * 64 + idx / 3];
    }
}

// ---------------- generic tiled GEMM: Y[N][M] = X[N][K] @ W[K][M] + bias ----------------
// block: 256 thr; tile 128 nodes x 64 cols (mtile = blockIdx.x*64); thread micro 8x4.
// (proven multi-block structure: many small blocks > in-block mtile loop on this chip)
__global__ __launch_bounds__(256) void k_gemm(const float* __restrict__ X, int ldx, int K,
                                              const float* __restrict__ W, int ldw,
                                              const float* __restrict__ bias,
                                              float* __restrict__ Y, float* __restrict__ Y2,
                                              int M) {
    __shared__ float sX[128 * 66];
    __shared__ float sW[64 * 64];
    int tid = threadIdx.x;
    int mtile = blockIdx.x * 64;
    int ntile = blockIdx.y * 128;
    int tc4 = (tid & 15) * 4;
    int tr = tid >> 4;
    float4 acc[8];
#pragma unroll
    for (int i = 0; i < 8; ++i) acc[i] = make_float4(0.f, 0.f, 0.f, 0.f);

    int nkc = K >> 6;
    for (int kc = 0; kc < nkc; ++kc) {
        if (kc) __syncthreads();
#pragma unroll
        for (int i = 0; i < 8; ++i) {
            int lin4 = (i * 256 + tid) * 4;
            int nl = lin4 >> 6, kk = lin4 & 63;
            int n = ntile + nl;
            float4 v = make_float4(0.f, 0.f, 0.f, 0.f);
            if (n < N_NODES) v = *(const float4*)(X + (size_t)n * ldx + kc * 64 + kk);
            float* d = sX + nl * 66 + kk;
            d[0] = v.x; d[1] = v.y; d[2] = v.z; d[3] = v.w;
        }
#pragma unroll
        for (int i = 0; i < 4; ++i) {
            int lin4 = (i * 256 + tid) * 4;
            int kk = lin4 >> 6, c = lin4 & 63;
            float4 v = *(const float4*)(W + (size_t)(kc * 64 + kk) * ldw + mtile + c);
            *(float4*)(sW + kk * 64 + c) = v;
        }
        __syncthreads();
        const float* xr = sX + tr * 8 * 66;
        const float* wr = sW + tc4;
        for (int kk = 0; kk < 64; kk += 2) {
            float4 wA = *(const float4*)(wr + kk * 64);
            float4 wB = *(const float4*)(wr + (kk + 1) * 64);
            float xA[8], xB[8];
#pragma unroll
            for (int i = 0; i < 8; ++i) { xA[i] = xr[i * 66 + kk]; xB[i] = xr[i * 66 + kk + 1]; }
#pragma unroll
            for (int i = 0; i < 8; ++i) {
                acc[i].x = fmaf(xA[i], wA.x, acc[i].x);
                acc[i].y = fmaf(xA[i], wA.y, acc[i].y);
                acc[i].z = fmaf(xA[i], wA.z, acc[i].z);
                acc[i].w = fmaf(xA[i], wA.w, acc[i].w);
            }
#pragma unroll
            for (int i = 0; i < 8; ++i) {
                acc[i].x = fmaf(xB[i], wB.x, acc[i].x);
                acc[i].y = fmaf(xB[i], wB.y, acc[i].y);
                acc[i].z = fmaf(xB[i], wB.z, acc[i].z);
                acc[i].w = fmaf(xB[i], wB.w, acc[i].w);
            }
        }
    }
    float4 bv = *(const float4*)(bias + mtile + tc4);
#pragma unroll
    for (int i = 0; i < 8; ++i) {
        int n = ntile + tr * 8 + i;
        if (n < N_NODES) {
            float4 y;
            y.x = acc[i].x + bv.x; y.y = acc[i].y + bv.y;
            y.z = acc[i].z + bv.z; y.w = acc[i].w + bv.w;
            *(float4*)(Y + (size_t)n * M + mtile + tc4) = y;
            if (Y2) *(float4*)(Y2 + (size_t)n * M + mtile + tc4) = y;
        }
    }
}

// ---------------- reduce GEMM: h = h0 = ann[N][256] @ rW[256][64] + rb ----------------
// K pipelined: next X/W chunk prefetched into registers while computing the current chunk.
__global__ __launch_bounds__(256) void k_gemm_red(const float* __restrict__ X,
                                                  const float* __restrict__ W,
                                                  const float* __restrict__ bias,
                                                  float* __restrict__ Y,
                                                  float* __restrict__ Y2) {
    __shared__ float sX[128 * 66];
    __shared__ float sW[64 * 64];
    int tid = threadIdx.x;
    int ntile = blockIdx.x * 128;
    int tc4 = (tid & 15) * 4;
    int tr = tid >> 4;
    int swr = tid >> 4;
    int swc = (tid & 15) * 4;

    float4 acc[8];
#pragma unroll
    for (int i = 0; i < 8; ++i) acc[i] = make_float4(0.f, 0.f, 0.f, 0.f);

    float4 xreg[8];
    float4 wreg[4];
#pragma unroll
    for (int i = 0; i < 8; ++i) {
        int lin4 = (i * 256 + tid) * 4;
        int nl = lin4 >> 6, kk = lin4 & 63;
        int n = ntile + nl;
        float4 v = make_float4(0.f, 0.f, 0.f, 0.f);
        if (n < N_NODES) v = *(const float4*)(X + (size_t)n * 256 + kk);
        xreg[i] = v;
    }
#pragma unroll
    for (int i = 0; i < 4; ++i)
        wreg[i] = *(const float4*)(W + (size_t)(i * 16 + swr) * 64 + swc);

    for (int kc = 0; kc < 4; ++kc) {
#pragma unroll
        for (int i = 0; i < 8; ++i) {
            int lin4 = (i * 256 + tid) * 4;
            int nl = lin4 >> 6, kk = lin4 & 63;
            float* d = sX + nl * 66 + kk;
            d[0] = xreg[i].x; d[1] = xreg[i].y; d[2] = xreg[i].z; d[3] = xreg[i].w;
        }
#pragma unroll
        for (int i = 0; i < 4; ++i)
            *(float4*)(sW + (i * 16 + swr) * 64 + swc) = wreg[i];
        __syncthreads();
        if (kc < 3) {
#pragma unroll
            for (int i = 0; i < 8; ++i) {
                int lin4 = (i * 256 + tid) * 4;
                int nl = lin4 >> 6, kk = lin4 & 63;
                int n = ntile + nl;
                float4 v = make_float4(0.f, 0.f, 0.f, 0.f);
                if (n < N_NODES) v = *(const float4*)(X + (size_t)n * 256 + (kc + 1) * 64 + kk);
                xreg[i] = v;
            }
#pragma unroll
            for (int i = 0; i < 4; ++i)
                wreg[i] = *(const float4*)(W + (size_t)((kc + 1) * 64 + i * 16 + swr) * 64 + swc);
        }
        const float* xr = sX + tr * 8 * 66;
        const float* wrp = sW + tc4;
        for (int kk = 0; kk < 64; kk += 2) {
            float4 wA = *(const float4*)(wrp + kk * 64);
            float4 wB = *(const float4*)(wrp + (kk + 1) * 64);
            float xA[8], xB[8];
#pragma unroll
            for (int i = 0; i < 8; ++i) { xA[i] = xr[i * 66 + kk]; xB[i] = xr[i * 66 + kk + 1]; }
#pragma unroll
            for (int i = 0; i < 8; ++i) {
                acc[i].x = fmaf(xA[i], wA.x, acc[i].x);
                acc[i].y = fmaf(xA[i], wA.y, acc[i].y);
                acc[i].z = fmaf(xA[i], wA.z, acc[i].z);
                acc[i].w = fmaf(xA[i], wA.w, acc[i].w);
            }
#pragma unroll
            for (int i = 0; i < 8; ++i) {
                acc[i].x = fmaf(xB[i], wB.x, acc[i].x);
                acc[i].y = fmaf(xB[i], wB.y, acc[i].y);
                acc[i].z = fmaf(xB[i], wB.z, acc[i].z);
                acc[i].w = fmaf(xB[i], wB.w, acc[i].w);
            }
        }
        if (kc < 3) __syncthreads();
    }
    float4 bv = *(const float4*)(bias + tc4);
#pragma unroll
    for (int i = 0; i < 8; ++i) {
        int n = ntile + tr * 8 + i;
        if (n < N_NODES) {
            float4 y;
            y.x = acc[i].x + bv.x; y.y = acc[i].y + bv.y;
            y.z = acc[i].z + bv.z; y.w = acc[i].w + bv.w;
            *(float4*)(Y + (size_t)n * 64 + tc4) = y;
            *(float4*)(Y2 + (size_t)n * 64 + tc4) = y;
        }
    }
}

// ---------------- edge aggregate: a[n] = sum of incoming trans rows from buf1 ----------------
// Vectorized: 16 lanes per edge, float4 per lane (one 1KB wave-load covers 4 edges);
// 4 loads batched per iteration for 4-deep MLP. FP accumulation order identical to the
// previous scalar version: per sub-group single accumulator, edges ascending; tail to sub0;
// final (a0+a1)+(a2+a3) via shfl tree. Bit-exact.
__global__ void k_aggregate(const float* __restrict__ buf1, const int* __restrict__ rs,
                            const int* __restrict__ colidx, float* __restrict__ a) {
    int l = threadIdx.x & 63;
    int n = blockIdx.x * 4 + (threadIdx.x >> 6);  // 25000 blocks * 4 = N exactly
    int sub = l >> 4;            // edge slot within group of 4
    int kq = (l & 15) * 4;       // k quad handled by this lane
    int beg = rs[n], end = rs[n + 1];             // wave-uniform
    float4 acc = make_float4(0.f, 0.f, 0.f, 0.f);
    int s = beg;
    // 16 edges per iteration: 4 independent gathers in flight per wave
    for (; s + 15 < end; s += 16) {
        int c0 = colidx[s + sub];
        int c1 = colidx[s + 4 + sub];
        int c2 = colidx[s + 8 + sub];
        int c3 = colidx[s + 12 + sub];
        float4 v0 = *(const float4*)(buf1 + (size_t)c0 + kq);
        float4 v1 = *(const float4*)(buf1 + (size_t)c1 + kq);
        float4 v2 = *(const float4*)(buf1 + (size_t)c2 + kq);
        float4 v3 = *(const float4*)(buf1 + (size_t)c3 + kq);
        acc.x += v0.x; acc.y += v0.y; acc.z += v0.z; acc.w += v0.w;
        acc.x += v1.x; acc.y += v1.y; acc.z += v1.z; acc.w += v1.w;
        acc.x += v2.x; acc.y += v2.y; acc.z += v2.z; acc.w += v2.w;
        acc.x += v3.x; acc.y += v3.y; acc.z += v3.z; acc.w += v3.w;
    }
    for (; s + 3 < end; s += 4) {
        int c = colidx[s + sub];
        float4 v = *(const float4*)(buf1 + (size_t)c + kq);
        acc.x += v.x; acc.y += v.y; acc.z += v.z; acc.w += v.w;
    }
    // tail (<4 edges): appended to sub-0 accumulator in order (matches old a0 semantics)
    for (; s < end; ++s) {
        if (sub == 0) {
            int c = colidx[s];
            float4 v = *(const float4*)(buf1 + (size_t)c + kq);
            acc.x += v.x; acc.y += v.y; acc.z += v.z; acc.w += v.w;
        }
    }
    // reduce: (a0+a1)+(a2+a3) per k element
    float4 t;
    t.x = acc.x + __shfl_xor(acc.x, 16, 64);
    t.y = acc.y + __shfl_xor(acc.y, 16, 64);
    t.z = acc.z + __shfl_xor(acc.z, 16, 64);
    t.w = acc.w + __shfl_xor(acc.w, 16, 64);
    float4 r;
    r.x = t.x + __shfl_xor(t.x, 32, 64);
    r.y = t.y + __shfl_xor(t.y, 32, 64);
    r.z = t.z + __shfl_xor(t.z, 32, 64);
    r.w = t.w + __shfl_xor(t.w, 32, 64);
    if (sub == 0) *(float4*)(a + (size_t)n * 64 + kq) = r;
}

// ---------------- fused dual-GEMM GRU: gi = a@WiA, gh = h@Wh192 (in-block), gates ---------
// Phase 0: gi from A; phase 1: gh from Hin (same tile rows, staged locally). Both use the
// identical ascending-k fma order as before, so gi/gh values are bit-exact with the old
// (k_gemm_step-gh + k_gruF-gi) pipeline. Saves the 77MB/step gh write+read via buf1.
__global__ __launch_bounds__(256) void k_gruF2(const float* __restrict__ A,
                                               const float* __restrict__ WiA,
                                               const float* __restrict__ biA,
                                               const float* __restrict__ Wh192,
                                               const float* __restrict__ bh192,
                                               float* __restrict__ H) {
    __shared__ float sX[64 * 34];
    __shared__ float sW[32 * 192];
    int tid = threadIdx.x;
    int ntile = blockIdx.x * 64;
    int tc = tid & 15;
    int tr = tid >> 4;
    float acc[2][4][12];
#pragma unroll
    for (int p = 0; p < 2; ++p)
#pragma unroll
        for (int i = 0; i < 4; ++i)
#pragma unroll
            for (int c = 0; c < 12; ++c) acc[p][i][c] = 0.f;

#pragma unroll
    for (int ph = 0; ph < 2; ++ph) {
        const float* Xsrc = (ph == 0) ? A : H;
        const float* Wsrc = (ph == 0) ? WiA : Wh192;
        for (int kc = 0; kc < 2; ++kc) {
            if (ph || kc) __syncthreads();   // prior readers of sX/sW done
#pragma unroll
            for (int i = 0; i < 2; ++i) {
                int lin4 = (i * 256 + tid) * 4;
                int nl = lin4 >> 5, kk = lin4 & 31;
                int n = ntile + nl;
                float4 v = make_float4(0.f, 0.f, 0.f, 0.f);
                if (n < N_NODES) v = *(const float4*)(Xsrc + (size_t)n * 64 + kc * 32 + kk);
                float* d = sX + nl * 34 + kk;
                d[0] = v.x; d[1] = v.y; d[2] = v.z; d[3] = v.w;
            }
            {
                int kk = tid >> 3, c = (tid & 7) * 24;
                const float* srcp = Wsrc + (size_t)(kc * 32 + kk) * 192 + c;
                float* d = sW + kk * 192 + c;
#pragma unroll
                for (int u = 0; u < 6; ++u) *(float4*)(d + 4 * u) = *(const float4*)(srcp + 4 * u);
            }
            __syncthreads();
            const float* xr = sX + tr * 4 * 34;
            const float* wr = sW + tc * 12;
            for (int kk = 0; kk < 32; kk += 2) {
                float4 w0 = *(const float4*)(wr + kk * 192);
                float4 w1 = *(const float4*)(wr + kk * 192 + 4);
                float4 w2 = *(const float4*)(wr + kk * 192 + 8);
                float4 u0 = *(const float4*)(wr + (kk + 1) * 192);
                float4 u1 = *(const float4*)(wr + (kk + 1) * 192 + 4);
                float4 u2 = *(const float4*)(wr + (kk + 1) * 192 + 8);
                float xA[4], xB[4];
#pragma unroll
                for (int i = 0; i < 4; ++i) { xA[i] = xr[i * 34 + kk]; xB[i] = xr[i * 34 + kk + 1]; }
#pragma unroll
                for (int i = 0; i < 4; ++i) {
                    acc[ph][i][0]  = fmaf(xA[i], w0.x, acc[ph][i][0]);
                    acc[ph][i][1]  = fmaf(xA[i], w0.y, acc[ph][i][1]);
                    acc[ph][i][2]  = fmaf(xA[i], w0.z, acc[ph][i][2]);
                    acc[ph][i][3]  = fmaf(xA[i], w0.w, acc[ph][i][3]);
                    acc[ph][i][4]  = fmaf(xA[i], w1.x, acc[ph][i][4]);
                    acc[ph][i][5]  = fmaf(xA[i], w1.y, acc[ph][i][5]);
                    acc[ph][i][6]  = fmaf(xA[i], w1.z, acc[ph][i][6]);
                    acc[ph][i][7]  = fmaf(xA[i], w1.w, acc[ph][i][7]);
                    acc[ph][i][8]  = fmaf(xA[i], w2.x, acc[ph][i][8]);
                    acc[ph][i][9]  = fmaf(xA[i], w2.y, acc[ph][i][9]);
                    acc[ph][i][10] = fmaf(xA[i], w2.z, acc[ph][i][10]);
                    acc[ph][i][11] = fmaf(xA[i], w2.w, acc[ph][i][11]);
                }
#pragma unroll
                for (int i = 0; i < 4; ++i) {
                    acc[ph][i][0]  = fmaf(xB[i], u0.x, acc[ph][i][0]);
                    acc[ph][i][1]  = fmaf(xB[i], u0.y, acc[ph][i][1]);
                    acc[ph][i][2]  = fmaf(xB[i], u0.z, acc[ph][i][2]);
                    acc[ph][i][3]  = fmaf(xB[i], u0.w, acc[ph][i][3]);
                    acc[ph][i][4]  = fmaf(xB[i], u1.x, acc[ph][i][4]);
                    acc[ph][i][5]  = fmaf(xB[i], u1.y, acc[ph][i][5]);
                    acc[ph][i][6]  = fmaf(xB[i], u1.z, acc[ph][i][6]);
                    acc[ph][i][7]  = fmaf(xB[i], u1.w, acc[ph][i][7]);
                    acc[ph][i][8]  = fmaf(xB[i], u2.x, acc[ph][i][8]);
                    acc[ph][i][9]  = fmaf(xB[i], u2.y, acc[ph][i][9]);
                    acc[ph][i][10] = fmaf(xB[i], u2.z, acc[ph][i][10]);
                    acc[ph][i][11] = fmaf(xB[i], u2.w, acc[ph][i][11]);
                }
            }
        }
    }
    // epilogue: GRU gate math. gg = gh_acc + bh (rounded first), matching the old buf1 path.
    float bb[12], bh[12];
    {
        float4 b0 = *(const float4*)(biA + tc * 12);
        float4 b1 = *(const float4*)(biA + tc * 12 + 4);
        float4 b2 = *(const float4*)(biA + tc * 12 + 8);
        bb[0] = b0.x; bb[1] = b0.y; bb[2] = b0.z; bb[3] = b0.w;
        bb[4] = b1.x; bb[5] = b1.y; bb[6] = b1.z; bb[7] = b1.w;
        bb[8] = b2.x; bb[9] = b2.y; bb[10] = b2.z; bb[11] = b2.w;
        float4 c0 = *(const float4*)(bh192 + tc * 12);
        float4 c1 = *(const float4*)(bh192 + tc * 12 + 4);
        float4 c2 = *(const float4*)(bh192 + tc * 12 + 8);
        bh[0] = c0.x; bh[1] = c0.y; bh[2] = c0.z; bh[3] = c0.w;
        bh[4] = c1.x; bh[5] = c1.y; bh[6] = c1.z; bh[7] = c1.w;
        bh[8] = c2.x; bh[9] = c2.y; bh[10] = c2.z; bh[11] = c2.w;
    }
#pragma unroll
    for (int i = 0; i < 4; ++i) {
        int n = ntile + tr * 4 + i;
        if (n >= N_NODES) continue;
        float gg[12];
#pragma unroll
        for (int c = 0; c < 12; ++c) gg[c] = acc[1][i][c] + bh[c];
        float4 hv = *(const float4*)(H + (size_t)n * 64 + tc * 4);
        float res[4];
#pragma unroll
        for (int jj = 0; jj < 4; ++jj) {
            int c = jj * 3;
            float r = sigmoidf_(acc[0][i][c] + bb[c] + gg[c]);
            float z = sigmoidf_(acc[0][i][c + 1] + bb[c + 1] + gg[c + 1]);
            float nn = tanhf(acc[0][i][c + 2] + bb[c + 2] + r * gg[c + 2]);
            float hj = (jj == 0) ? hv.x : (jj == 1) ? hv.y : (jj == 2) ? hv.z : hv.w;
            res[jj] = (1.f - z) * nn + z * hj;
        }
        float4 o; o.x = res[0]; o.y = res[1]; o.z = res[2]; o.w = res[3];
        *(float4*)(H + (size_t)n * 64 + tc * 4) = o;
    }
}

// ---------------- pooling: segmented, atomic-free, multi-block per graph ----------------
__global__ void k_bounds(const int* __restrict__ gid, int* __restrict__ start) {
    int n = blockIdx.x * 256 + threadIdx.x;
    if (n < N_NODES) {
        int g = gid[n];
        if (n == 0) {
            for (int x = 0; x <= g; ++x) start[x] = 0;
        } else {
            int pg = gid[n - 1];
            for (int x = pg + 1; x <= g; ++x) start[x] = n;
        }
        if (n == N_NODES - 1) {
            for (int x = g + 1; x <= NGRAPH; ++x) start[x] = N_NODES;
        }
    }
}

__global__ void k_gate2(const float* __restrict__ H, const float* __restrict__ H0,
                        const float* __restrict__ gW, const float* __restrict__ gb,
                        float* __restrict__ gate) {
    int l = threadIdx.x & 63;
    int n = blockIdx.x * 4 + (threadIdx.x >> 6);
    float v = H[(size_t)n * 64 + l] * gW[l] + H0[(size_t)n * 64 + l] * gW[64 + l];
    for (int off = 32; off > 0; off >>= 1) v += __shfl_xor(v, off, 64);
    if (l == 0) gate[n] = v + gb[0];
}

__global__ __launch_bounds__(64) void k_poolA(const float* __restrict__ gate,
                                              const int* __restrict__ start,
                                              float* __restrict__ pmax) {
    int g = blockIdx.x, s = blockIdx.y;
    int beg = start[g], len = start[g + 1] - beg;
    int sb = beg + (int)((long long)len * s / PS);
    int se = beg + (int)((long long)len * (s + 1) / PS);
    float m = -INFINITY;
    for (int n = sb + threadIdx.x; n < se; n += 64) m = fmaxf(m, gate[n]);
    for (int off = 32; off > 0; off >>= 1) m = fmaxf(m, __shfl_xor(m, off, 64));
    if (threadIdx.x == 0) pmax[g * PS + s] = m;
}

__global__ void k_poolB(const float* __restrict__ pmax, float* __restrict__ gm) {
    int g = threadIdx.x;  // 64 threads
    float m = -INFINITY;
    for (int s = 0; s < PS; ++s) m = fmaxf(m, pmax[g * PS + s]);
    if (!isfinite(m)) m = 0.0f;   // reference's empty-graph guard
    gm[g] = m;
}

__global__ __launch_bounds__(256) void k_poolC(const float* __restrict__ H,
                                               const float* __restrict__ H0,
                                               const float* __restrict__ gate,
                                               const int* __restrict__ start,
                                               const float* __restrict__ gm,
                                               float* __restrict__ pnum,
                                               float* __restrict__ pden) {
    int g = blockIdx.x, s = blockIdx.y;
    int beg = start[g], len = start[g + 1] - beg;
    int sb = beg + (int)((long long)len * s / PS);
    int se = beg + (int)((long long)len * (s + 1) / PS);
    int t = threadIdx.x;
    int lane = t & 63, wave = t >> 6;
    float m = gm[g];
    __shared__ float shh[4][64], sh0[4][64], ses[4];
    float ah = 0.f, ah0 = 0.f, es = 0.f;
    for (int n = sb + wave; n < se; n += 4) {
        float e = expf(gate[n] - m);
        es += e;
        ah  += e * H [(size_t)n * 64 + lane];
        ah0 += e * H0[(size_t)n * 64 + lane];
    }
    shh[wave][lane] = ah; sh0[wave][lane] = ah0;
    if (lane == 0) ses[wave] = es;
    __syncthreads();
    if (wave == 0) {
        float r  = shh[0][lane] + shh[1][lane] + shh[2][lane] + shh[3][lane];
        float r0 = sh0[0][lane] + sh0[1][lane] + sh0[2][lane] + sh0[3][lane];
        int base = (g * PS + s) * 128;
        pnum[base + lane]      = r;
        pnum[base + 64 + lane] = r0;
        if (lane == 0) pden[g * PS + s] = ses[0] + ses[1] + ses[2] + ses[3];
    }
}

__global__ __launch_bounds__(128) void k_poolD(const float* __restrict__ pnum,
                                               const float* __restrict__ pden,
                                               float* __restrict__ ro) {
    int g = blockIdx.x;
    int c = threadIdx.x;
    float den = 0.f;
    for (int s = 0; s < PS; ++s) den += pden[g * PS + s];
    float nu = 0.f;
    for (int s = 0; s < PS; ++s) nu += pnum[(g * PS + s) * 128 + c];
    ro[g * 128 + c] = (den > 0.f) ? nu / den : 0.f;
}

__global__ void k_logits(const float* __restrict__ ro, const float* __restrict__ oW,
                         const float* __restrict__ ob, float* __restrict__ out) {
    int t = threadIdx.x;
    int b = t >> 1;
    int c = t & 1;
    float acc = ob[c];
    for (int k = 0; k < 128; ++k) acc = fmaf(ro[b * 128 + k], oW[k * 2 + c], acc);
    out[b * 2 + c] = acc;
}

extern "C" void kernel_launch(void* const* d_in, const int* in_sizes, int n_in,
                              void* d_out, int out_size, void* d_ws, size_t ws_size,
                              hipStream_t stream) {
    (void)in_sizes; (void)n_in; (void)out_size; (void)ws_size;
    const float* ann = (const float*)d_in[0];
    const int* src   = (const int*)d_in[1];
    const int* dst   = (const int*)d_in[2];
    const int* ety   = (const int*)d_in[3];
    const int* gid   = (const int*)d_in[4];
    const float* rW  = (const float*)d_in[5];
    const float* rb  = (const float*)d_in[6];
    const float* eW  = (const float*)d_in[7];
    const float* eb  = (const float*)d_in[8];
    const float* Wi  = (const float*)d_in[9];
    const float* Bi  = (const float*)d_in[10];
    const float* Wh  = (const float*)d_in[11];
    const float* Bh  = (const float*)d_in[12];
    const float* gW  = (const float*)d_in[13];
    const float* gb  = (const float*)d_in[14];
    const float* oW  = (const float*)d_in[15];
    const float* ob  = (const float*)d_in[16];
    float* out = (float*)d_out;

    char* p = (char*)d_ws;
    auto take = [&](size_t nbytes) -> void* {
        void* r = (void*)p;
        p += (nbytes + 255) & ~((size_t)255);
        return r;
    };
    float* h0      = (float*)take((size_t)N_NODES * 64 * 4);
    float* h       = (float*)take((size_t)N_NODES * 64 * 4);
    float* abuf    = (float*)take((size_t)N_NODES * 64 * 4);
    float* buf1    = (float*)take((size_t)N_NODES * 256 * 4);   // trans only [N][4*64]
    float* W256    = (float*)take(64 * 256 * 4);
    float* b256    = (float*)take(256 * 4);
    float* Wh192   = (float*)take(64 * 192 * 4);
    float* bh192   = (float*)take(192 * 4);
    float* WiA     = (float*)take(64 * 192 * 4);
    float* biA     = (float*)take(192 * 4);
    int* deg       = (int*)take((size_t)N_NODES * 4);
    int* cur       = (int*)take((size_t)N_NODES * 4);
    int* rs        = (int*)take((size_t)(N_NODES + 1) * 4);
    int* part      = (int*)take(512);
    int* colidx    = (int*)take((size_t)N_EDGES * 4);
    float* gate    = (float*)take((size_t)N_NODES * 4);
    int* start     = (int*)take((size_t)(NGRAPH + 1) * 4);
    float* pmax    = (float*)take(NGRAPH * PS * 4);
    float* gm      = (float*)take(NGRAPH * 4);
    float* pnum    = (float*)take((size_t)NGRAPH * PS * 128 * 4);
    float* pden    = (float*)take(NGRAPH * PS * 4);
    float* ro      = (float*)take(NGRAPH * 128 * 4);

    // ---- CSR build (by dst)
    hipMemsetAsync(deg, 0, (size_t)N_NODES * 4, stream);
    hipMemsetAsync(cur, 0, (size_t)N_NODES * 4, stream);
    k_count<<<(N_EDGES + 255) / 256, 256, 0, stream>>>(dst, deg);
    int nb = (N_NODES + 1023) / 1024;  // 98
    k_scan1<<<nb, 256, 0, stream>>>(deg, rs, part);
    k_scan2<<<1, 64, 0, stream>>>(part, rs, nb);
    k_scan3<<<(N_NODES + 255) / 256, 256, 0, stream>>>(rs, part);
    k_fill<<<(N_EDGES + 255) / 256, 256, 0, stream>>>(src, dst, ety, rs, cur, colidx);

    // ---- weight prep + graph bounds
    k_prep2<<<112, 256, 0, stream>>>(Wh, Bh, eW, eb, Wi, Bi, W256, b256, Wh192, bh192, WiA, biA);
    k_bounds<<<(N_NODES + 255) / 256, 256, 0, stream>>>(gid, start);

    int ntiles = (N_NODES + 127) / 128;  // 782

    // ---- reduce layer: h = h0 = ann @ rW + rb (K-pipelined)
    k_gemm_red<<<ntiles, 256, 0, stream>>>(ann, rW, rb, h, h0);

    // ---- message-passing steps: trans-only GEMM (M=256), vectorized aggregate, dual-GEMM GRU
    for (int s = 0; s < NSTEPS; ++s) {
        k_gemm<<<dim3(4, ntiles), 256, 0, stream>>>(h, 64, 64, W256, 256, b256,
                                                    buf1, nullptr, 256);
        k_aggregate<<<N_NODES / 4, 256, 0, stream>>>(buf1, rs, colidx, abuf);
        k_gruF2<<<(N_NODES + 63) / 64, 256, 0, stream>>>(abuf, WiA, biA, Wh192, bh192, h);
    }

    // ---- pooling + classifier (atomic-free, multi-block)
    k_gate2<<<N_NODES / 4, 256, 0, stream>>>(h, h0, gW, gb, gate);
    k_poolA<<<dim3(NGRAPH, PS), 64, 0, stream>>>(gate, start, pmax);
    k_poolB<<<1, 64, 0, stream>>>(pmax, gm);
    k_poolC<<<dim3(NGRAPH, PS), 256, 0, stream>>>(h, h0, gate, start, gm, pnum, pden);
    k_poolD<<<NGRAPH, 128, 0, stream>>>(pnum, pden, ro);
    k_logits<<<1, 128, 0, stream>>>(ro, oW, ob, out);
}

// Round 4
// 1512.554 us; speedup vs baseline: 1.1379x; 1.0359x over previous
//
#include <hip/hip_runtime.h>
#include <cstdint>
#include <cstddef>

#define N_NODES 100000
#define N_EDGES 1200000
#define ASIZE 256
#define HSIZE 64
#define NTYPES 4
#define NSTEPS 6
#define NGRAPH 64
#define PS 16   // pooling splits per graph

static __device__ __forceinline__ float sigmoidf_(float x) { return 1.0f / (1.0f + expf(-x)); }

// ---------------- CSR build (by dst) ----------------
__global__ void k_count(const int* __restrict__ dst, int* __restrict__ deg) {
    int e = blockIdx.x * 256 + threadIdx.x;
    if (e < N_EDGES) atomicAdd(&deg[dst[e]], 1);
}

__global__ void k_scan1(const int* __restrict__ deg, int* __restrict__ rs, int* __restrict__ part) {
    __shared__ int sh[256];
    int t = threadIdx.x;
    int base = blockIdx.x * 1024 + t * 4;
    int v0 = (base + 0 < N_NODES) ? deg[base + 0] : 0;
    int v1 = (base + 1 < N_NODES) ? deg[base + 1] : 0;
    int v2 = (base + 2 < N_NODES) ? deg[base + 2] : 0;
    int v3 = (base + 3 < N_NODES) ? deg[base + 3] : 0;
    int s = v0 + v1 + v2 + v3;
    sh[t] = s;
    __syncthreads();
    for (int off = 1; off < 256; off <<= 1) {
        int x = (t >= off) ? sh[t - off] : 0;
        __syncthreads();
        sh[t] += x;
        __syncthreads();
    }
    int excl = sh[t] - s;
    if (t == 255) part[blockIdx.x] = sh[255];
    if (base + 0 < N_NODES) rs[base + 0] = excl;
    if (base + 1 < N_NODES) rs[base + 1] = excl + v0;
    if (base + 2 < N_NODES) rs[base + 2] = excl + v0 + v1;
    if (base + 3 < N_NODES) rs[base + 3] = excl + v0 + v1 + v2;
}

__global__ void k_scan2(int* __restrict__ part, int* __restrict__ rs, int nb) {
    if (threadIdx.x == 0 && blockIdx.x == 0) {
        int run = 0;
        for (int i = 0; i < nb; ++i) { int v = part[i]; part[i] = run; run += v; }
        rs[N_NODES] = run;
    }
}

__global__ void k_scan3(int* __restrict__ rs, const int* __restrict__ part) {
    int i = blockIdx.x * 256 + threadIdx.x;
    if (i < N_NODES) rs[i] += part[i >> 10];
}

// colidx holds a precomputed float-offset into buf1 ([N][256] trans-only): src*256 + ety*64
__global__ void k_fill(const int* __restrict__ src, const int* __restrict__ dst,
                       const int* __restrict__ ety, const int* __restrict__ rs,
                       int* __restrict__ cur, int* __restrict__ colidx) {
    int e = blockIdx.x * 256 + threadIdx.x;
    if (e < N_EDGES) {
        int d = dst[e];
        int pos = rs[d] + atomicAdd(&cur[d], 1);
        colidx[pos] = src[e] * 256 + ety[e] * 64;
    }
}

// ---------------- weight prep ----------------
__global__ void k_prep2(const float* __restrict__ Wh, const float* __restrict__ Bh,
                        const float* __restrict__ eW, const float* __restrict__ eb,
                        const float* __restrict__ Wi, const float* __restrict__ Bi,
                        float* __restrict__ W256, float* __restrict__ b256,
                        float* __restrict__ Wh192, float* __restrict__ bh192,
                        float* __restrict__ WiA, float* __restrict__ biA) {
    int idx = blockIdx.x * 256 + threadIdx.x;
    if (idx < 64 * 256) {
        int k = idx / 256, c = idx % 256;
        W256[idx] = eW[(size_t)(c >> 6) * 4096 + k * 64 + (c & 63)];
    }
    if (idx < 64 * 192) {
        int k = idx / 192, m = idx % 192;
        int j = m / 3, g = m % 3;
        WiA[idx]   = Wi[(g * 64 + j) * 64 + k];
        Wh192[idx] = Wh[(g * 64 + j) * 64 + k];
    }
    if (idx < 256) b256[idx] = eb[idx];
    if (idx < 192) {
        biA[idx]   = Bi[(idx % 3) * 64 + idx / 3];
        bh192[idx] = Bh[(idx % 3) * 64 + idx / 3];
    }
}

// ---------------- generic tiled GEMM (used once: pre-loop trans of h0) ----------------
__global__ __launch_bounds__(256) void k_gemm(const float* __restrict__ X, int ldx, int K,
                                              const float* __restrict__ W, int ldw,
                                              const float* __restrict__ bias,
                                              float* __restrict__ Y, float* __restrict__ Y2,
                                              int M) {
    __shared__ float sX[128 * 66];
    __shared__ float sW[64 * 64];
    int tid = threadIdx.x;
    int mtile = blockIdx.x * 64;
    int ntile = blockIdx.y * 128;
    int tc4 = (tid & 15) * 4;
    int tr = tid >> 4;
    float4 acc[8];
#pragma unroll
    for (int i = 0; i < 8; ++i) acc[i] = make_float4(0.f, 0.f, 0.f, 0.f);

    int nkc = K >> 6;
    for (int kc = 0; kc < nkc; ++kc) {
        if (kc) __syncthreads();
#pragma unroll
        for (int i = 0; i < 8; ++i) {
            int lin4 = (i * 256 + tid) * 4;
            int nl = lin4 >> 6, kk = lin4 & 63;
            int n = ntile + nl;
            float4 v = make_float4(0.f, 0.f, 0.f, 0.f);
            if (n < N_NODES) v = *(const float4*)(X + (size_t)n * ldx + kc * 64 + kk);
            float* d = sX + nl * 66 + kk;
            d[0] = v.x; d[1] = v.y; d[2] = v.z; d[3] = v.w;
        }
#pragma unroll
        for (int i = 0; i < 4; ++i) {
            int lin4 = (i * 256 + tid) * 4;
            int kk = lin4 >> 6, c = lin4 & 63;
            float4 v = *(const float4*)(W + (size_t)(kc * 64 + kk) * ldw + mtile + c);
            *(float4*)(sW + kk * 64 + c) = v;
        }
        __syncthreads();
        const float* xr = sX + tr * 8 * 66;
        const float* wr = sW + tc4;
        for (int kk = 0; kk < 64; kk += 2) {
            float4 wA = *(const float4*)(wr + kk * 64);
            float4 wB = *(const float4*)(wr + (kk + 1) * 64);
            float xA[8], xB[8];
#pragma unroll
            for (int i = 0; i < 8; ++i) { xA[i] = xr[i * 66 + kk]; xB[i] = xr[i * 66 + kk + 1]; }
#pragma unroll
            for (int i = 0; i < 8; ++i) {
                acc[i].x = fmaf(xA[i], wA.x, acc[i].x);
                acc[i].y = fmaf(xA[i], wA.y, acc[i].y);
                acc[i].z = fmaf(xA[i], wA.z, acc[i].z);
                acc[i].w = fmaf(xA[i], wA.w, acc[i].w);
            }
#pragma unroll
            for (int i = 0; i < 8; ++i) {
                acc[i].x = fmaf(xB[i], wB.x, acc[i].x);
                acc[i].y = fmaf(xB[i], wB.y, acc[i].y);
                acc[i].z = fmaf(xB[i], wB.z, acc[i].z);
                acc[i].w = fmaf(xB[i], wB.w, acc[i].w);
            }
        }
    }
    float4 bv = *(const float4*)(bias + mtile + tc4);
#pragma unroll
    for (int i = 0; i < 8; ++i) {
        int n = ntile + tr * 8 + i;
        if (n < N_NODES) {
            float4 y;
            y.x = acc[i].x + bv.x; y.y = acc[i].y + bv.y;
            y.z = acc[i].z + bv.z; y.w = acc[i].w + bv.w;
            *(float4*)(Y + (size_t)n * M + mtile + tc4) = y;
            if (Y2) *(float4*)(Y2 + (size_t)n * M + mtile + tc4) = y;
        }
    }
}

// ---------------- reduce GEMM: h = h0 = ann[N][256] @ rW[256][64] + rb (K-pipelined) -------
__global__ __launch_bounds__(256) void k_gemm_red(const float* __restrict__ X,
                                                  const float* __restrict__ W,
                                                  const float* __restrict__ bias,
                                                  float* __restrict__ Y,
                                                  float* __restrict__ Y2) {
    __shared__ float sX[128 * 66];
    __shared__ float sW[64 * 64];
    int tid = threadIdx.x;
    int ntile = blockIdx.x * 128;
    int tc4 = (tid & 15) * 4;
    int tr = tid >> 4;
    int swr = tid >> 4;
    int swc = (tid & 15) * 4;

    float4 acc[8];
#pragma unroll
    for (int i = 0; i < 8; ++i) acc[i] = make_float4(0.f, 0.f, 0.f, 0.f);

    float4 xreg[8];
    float4 wreg[4];
#pragma unroll
    for (int i = 0; i < 8; ++i) {
        int lin4 = (i * 256 + tid) * 4;
        int nl = lin4 >> 6, kk = lin4 & 63;
        int n = ntile + nl;
        float4 v = make_float4(0.f, 0.f, 0.f, 0.f);
        if (n < N_NODES) v = *(const float4*)(X + (size_t)n * 256 + kk);
        xreg[i] = v;
    }
#pragma unroll
    for (int i = 0; i < 4; ++i)
        wreg[i] = *(const float4*)(W + (size_t)(i * 16 + swr) * 64 + swc);

    for (int kc = 0; kc < 4; ++kc) {
#pragma unroll
        for (int i = 0; i < 8; ++i) {
            int lin4 = (i * 256 + tid) * 4;
            int nl = lin4 >> 6, kk = lin4 & 63;
            float* d = sX + nl * 66 + kk;
            d[0] = xreg[i].x; d[1] = xreg[i].y; d[2] = xreg[i].z; d[3] = xreg[i].w;
        }
#pragma unroll
        for (int i = 0; i < 4; ++i)
            *(float4*)(sW + (i * 16 + swr) * 64 + swc) = wreg[i];
        __syncthreads();
        if (kc < 3) {
#pragma unroll
            for (int i = 0; i < 8; ++i) {
                int lin4 = (i * 256 + tid) * 4;
                int nl = lin4 >> 6, kk = lin4 & 63;
                int n = ntile + nl;
                float4 v = make_float4(0.f, 0.f, 0.f, 0.f);
                if (n < N_NODES) v = *(const float4*)(X + (size_t)n * 256 + (kc + 1) * 64 + kk);
                xreg[i] = v;
            }
#pragma unroll
            for (int i = 0; i < 4; ++i)
                wreg[i] = *(const float4*)(W + (size_t)((kc + 1) * 64 + i * 16 + swr) * 64 + swc);
        }
        const float* xr = sX + tr * 8 * 66;
        const float* wrp = sW + tc4;
        for (int kk = 0; kk < 64; kk += 2) {
            float4 wA = *(const float4*)(wrp + kk * 64);
            float4 wB = *(const float4*)(wrp + (kk + 1) * 64);
            float xA[8], xB[8];
#pragma unroll
            for (int i = 0; i < 8; ++i) { xA[i] = xr[i * 66 + kk]; xB[i] = xr[i * 66 + kk + 1]; }
#pragma unroll
            for (int i = 0; i < 8; ++i) {
                acc[i].x = fmaf(xA[i], wA.x, acc[i].x);
                acc[i].y = fmaf(xA[i], wA.y, acc[i].y);
                acc[i].z = fmaf(xA[i], wA.z, acc[i].z);
                acc[i].w = fmaf(xA[i], wA.w, acc[i].w);
            }
#pragma unroll
            for (int i = 0; i < 8; ++i) {
                acc[i].x = fmaf(xB[i], wB.x, acc[i].x);
                acc[i].y = fmaf(xB[i], wB.y, acc[i].y);
                acc[i].z = fmaf(xB[i], wB.z, acc[i].z);
                acc[i].w = fmaf(xB[i], wB.w, acc[i].w);
            }
        }
        if (kc < 3) __syncthreads();
    }
    float4 bv = *(const float4*)(bias + tc4);
#pragma unroll
    for (int i = 0; i < 8; ++i) {
        int n = ntile + tr * 8 + i;
        if (n < N_NODES) {
            float4 y;
            y.x = acc[i].x + bv.x; y.y = acc[i].y + bv.y;
            y.z = acc[i].z + bv.z; y.w = acc[i].w + bv.w;
            *(float4*)(Y + (size_t)n * 64 + tc4) = y;
            *(float4*)(Y2 + (size_t)n * 64 + tc4) = y;
        }
    }
}

// ---------------- edge aggregate: a[n] = sum of incoming trans rows from buf1 ----------------
// 16 lanes per edge x float4; 8 gathers in flight (deeper MLP). Per-sub accumulation
// sequence (ascending edges, stride 4, start beg+sub) identical to before -> bit-exact.
__global__ void k_aggregate(const float* __restrict__ buf1, const int* __restrict__ rs,
                            const int* __restrict__ colidx, float* __restrict__ a) {
    int l = threadIdx.x & 63;
    int n = blockIdx.x * 4 + (threadIdx.x >> 6);  // 25000 blocks * 4 = N exactly
    int sub = l >> 4;            // edge slot within group of 4
    int kq = (l & 15) * 4;       // k quad handled by this lane
    int beg = rs[n], end = rs[n + 1];             // wave-uniform
    float4 acc = make_float4(0.f, 0.f, 0.f, 0.f);
    int s = beg;
    for (; s + 31 < end; s += 32) {
        int c0 = colidx[s + sub];
        int c1 = colidx[s + 4 + sub];
        int c2 = colidx[s + 8 + sub];
        int c3 = colidx[s + 12 + sub];
        int c4 = colidx[s + 16 + sub];
        int c5 = colidx[s + 20 + sub];
        int c6 = colidx[s + 24 + sub];
        int c7 = colidx[s + 28 + sub];
        float4 v0 = *(const float4*)(buf1 + (size_t)c0 + kq);
        float4 v1 = *(const float4*)(buf1 + (size_t)c1 + kq);
        float4 v2 = *(const float4*)(buf1 + (size_t)c2 + kq);
        float4 v3 = *(const float4*)(buf1 + (size_t)c3 + kq);
        float4 v4 = *(const float4*)(buf1 + (size_t)c4 + kq);
        float4 v5 = *(const float4*)(buf1 + (size_t)c5 + kq);
        float4 v6 = *(const float4*)(buf1 + (size_t)c6 + kq);
        float4 v7 = *(const float4*)(buf1 + (size_t)c7 + kq);
        acc.x += v0.x; acc.y += v0.y; acc.z += v0.z; acc.w += v0.w;
        acc.x += v1.x; acc.y += v1.y; acc.z += v1.z; acc.w += v1.w;
        acc.x += v2.x; acc.y += v2.y; acc.z += v2.z; acc.w += v2.w;
        acc.x += v3.x; acc.y += v3.y; acc.z += v3.z; acc.w += v3.w;
        acc.x += v4.x; acc.y += v4.y; acc.z += v4.z; acc.w += v4.w;
        acc.x += v5.x; acc.y += v5.y; acc.z += v5.z; acc.w += v5.w;
        acc.x += v6.x; acc.y += v6.y; acc.z += v6.z; acc.w += v6.w;
        acc.x += v7.x; acc.y += v7.y; acc.z += v7.z; acc.w += v7.w;
    }
    for (; s + 3 < end; s += 4) {
        int c = colidx[s + sub];
        float4 v = *(const float4*)(buf1 + (size_t)c + kq);
        acc.x += v.x; acc.y += v.y; acc.z += v.z; acc.w += v.w;
    }
    for (; s < end; ++s) {
        if (sub == 0) {
            int c = colidx[s];
            float4 v = *(const float4*)(buf1 + (size_t)c + kq);
            acc.x += v.x; acc.y += v.y; acc.z += v.z; acc.w += v.w;
        }
    }
    float4 t;
    t.x = acc.x + __shfl_xor(acc.x, 16, 64);
    t.y = acc.y + __shfl_xor(acc.y, 16, 64);
    t.z = acc.z + __shfl_xor(acc.z, 16, 64);
    t.w = acc.w + __shfl_xor(acc.w, 16, 64);
    float4 r;
    r.x = t.x + __shfl_xor(t.x, 32, 64);
    r.y = t.y + __shfl_xor(t.y, 32, 64);
    r.z = t.z + __shfl_xor(t.z, 32, 64);
    r.w = t.w + __shfl_xor(t.w, 32, 64);
    if (sub == 0) *(float4*)(a + (size_t)n * 64 + kq) = r;
}

// ---------------- fused: gi-GEMM + gh-GEMM + GRU + trans-GEMM for next step ----------------
// Tile: 64 nodes. Phases 0/1: gi = a@WiA, gh = h@Wh192 (transposed-X LDS, b128 reads).
// Epilogue: GRU -> h_new (registers) -> global H + LDS sHT (transposed).
// Trans tail (if do_trans): buf1[n][256] = h_new @ W256 + b256, staged per 64-col chunk.
// All fma chains ascending-k, wA-then-wB -> bit-exact vs the previous 3-kernel pipeline.
__global__ __launch_bounds__(256) void k_gruF3(const float* __restrict__ A,
                                               const float* __restrict__ WiA,
                                               const float* __restrict__ biA,
                                               const float* __restrict__ Wh192,
                                               const float* __restrict__ bh192,
                                               const float* __restrict__ W256,
                                               const float* __restrict__ b256,
                                               float* __restrict__ H,
                                               float* __restrict__ buf1,
                                               int do_trans) {
    __shared__ float sXT[32 * 68];   // [k][node], stride 68 (16B-aligned rows)
    __shared__ float sW[32 * 192];   // gi/gh W chunks; reused as [64][64] for trans chunks
    __shared__ float sHT[64 * 68];   // h_new transposed [k][node]
    int tid = threadIdx.x;
    int ntile = blockIdx.x * 64;
    int tc = tid & 15;
    int tr = tid >> 4;
    float acc[2][4][12];
#pragma unroll
    for (int p = 0; p < 2; ++p)
#pragma unroll
        for (int i = 0; i < 4; ++i)
#pragma unroll
            for (int c = 0; c < 12; ++c) acc[p][i][c] = 0.f;

#pragma unroll
    for (int ph = 0; ph < 2; ++ph) {
        const float* Xsrc = (ph == 0) ? A : H;
        const float* Wsrc = (ph == 0) ? WiA : Wh192;
        for (int kc = 0; kc < 2; ++kc) {
            if (ph || kc) __syncthreads();
            // stage X transposed: 64 nodes x 32 k
#pragma unroll
            for (int i = 0; i < 2; ++i) {
                int lin = i * 256 + tid;             // 0..511 float4s
                int nl = lin >> 3;                   // node 0..63
                int kk = (lin & 7) * 4;              // k 0..28
                int n = ntile + nl;
                float4 v = make_float4(0.f, 0.f, 0.f, 0.f);
                if (n < N_NODES) v = *(const float4*)(Xsrc + (size_t)n * 64 + kc * 32 + kk);
                sXT[(kk + 0) * 68 + nl] = v.x;
                sXT[(kk + 1) * 68 + nl] = v.y;
                sXT[(kk + 2) * 68 + nl] = v.z;
                sXT[(kk + 3) * 68 + nl] = v.w;
            }
            {
                int kk = tid >> 3, c = (tid & 7) * 24;
                const float* srcp = Wsrc + (size_t)(kc * 32 + kk) * 192 + c;
                float* d = sW + kk * 192 + c;
#pragma unroll
                for (int u = 0; u < 6; ++u) *(float4*)(d + 4 * u) = *(const float4*)(srcp + 4 * u);
            }
            __syncthreads();
            const float* wr = sW + tc * 12;
            for (int kk = 0; kk < 32; kk += 2) {
                float4 w0 = *(const float4*)(wr + kk * 192);
                float4 w1 = *(const float4*)(wr + kk * 192 + 4);
                float4 w2 = *(const float4*)(wr + kk * 192 + 8);
                float4 u0 = *(const float4*)(wr + (kk + 1) * 192);
                float4 u1 = *(const float4*)(wr + (kk + 1) * 192 + 4);
                float4 u2 = *(const float4*)(wr + (kk + 1) * 192 + 8);
                float4 xA4 = *(const float4*)(sXT + kk * 68 + tr * 4);
                float4 xB4 = *(const float4*)(sXT + (kk + 1) * 68 + tr * 4);
                float xA[4] = {xA4.x, xA4.y, xA4.z, xA4.w};
                float xB[4] = {xB4.x, xB4.y, xB4.z, xB4.w};
#pragma unroll
                for (int i = 0; i < 4; ++i) {
                    acc[ph][i][0]  = fmaf(xA[i], w0.x, acc[ph][i][0]);
                    acc[ph][i][1]  = fmaf(xA[i], w0.y, acc[ph][i][1]);
                    acc[ph][i][2]  = fmaf(xA[i], w0.z, acc[ph][i][2]);
                    acc[ph][i][3]  = fmaf(xA[i], w0.w, acc[ph][i][3]);
                    acc[ph][i][4]  = fmaf(xA[i], w1.x, acc[ph][i][4]);
                    acc[ph][i][5]  = fmaf(xA[i], w1.y, acc[ph][i][5]);
                    acc[ph][i][6]  = fmaf(xA[i], w1.z, acc[ph][i][6]);
                    acc[ph][i][7]  = fmaf(xA[i], w1.w, acc[ph][i][7]);
                    acc[ph][i][8]  = fmaf(xA[i], w2.x, acc[ph][i][8]);
                    acc[ph][i][9]  = fmaf(xA[i], w2.y, acc[ph][i][9]);
                    acc[ph][i][10] = fmaf(xA[i], w2.z, acc[ph][i][10]);
                    acc[ph][i][11] = fmaf(xA[i], w2.w, acc[ph][i][11]);
                }
#pragma unroll
                for (int i = 0; i < 4; ++i) {
                    acc[ph][i][0]  = fmaf(xB[i], u0.x, acc[ph][i][0]);
                    acc[ph][i][1]  = fmaf(xB[i], u0.y, acc[ph][i][1]);
                    acc[ph][i][2]  = fmaf(xB[i], u0.z, acc[ph][i][2]);
                    acc[ph][i][3]  = fmaf(xB[i], u0.w, acc[ph][i][3]);
                    acc[ph][i][4]  = fmaf(xB[i], u1.x, acc[ph][i][4]);
                    acc[ph][i][5]  = fmaf(xB[i], u1.y, acc[ph][i][5]);
                    acc[ph][i][6]  = fmaf(xB[i], u1.z, acc[ph][i][6]);
                    acc[ph][i][7]  = fmaf(xB[i], u1.w, acc[ph][i][7]);
                    acc[ph][i][8]  = fmaf(xB[i], u2.x, acc[ph][i][8]);
                    acc[ph][i][9]  = fmaf(xB[i], u2.y, acc[ph][i][9]);
                    acc[ph][i][10] = fmaf(xB[i], u2.z, acc[ph][i][10]);
                    acc[ph][i][11] = fmaf(xB[i], u2.w, acc[ph][i][11]);
                }
            }
        }
    }
    // epilogue: GRU gates; write h_new to global H and (transposed) to sHT
    float bb[12], bh[12];
    {
        float4 b0 = *(const float4*)(biA + tc * 12);
        float4 b1 = *(const float4*)(biA + tc * 12 + 4);
        float4 b2 = *(const float4*)(biA + tc * 12 + 8);
        bb[0] = b0.x; bb[1] = b0.y; bb[2] = b0.z; bb[3] = b0.w;
        bb[4] = b1.x; bb[5] = b1.y; bb[6] = b1.z; bb[7] = b1.w;
        bb[8] = b2.x; bb[9] = b2.y; bb[10] = b2.z; bb[11] = b2.w;
        float4 c0 = *(const float4*)(bh192 + tc * 12);
        float4 c1 = *(const float4*)(bh192 + tc * 12 + 4);
        float4 c2 = *(const float4*)(bh192 + tc * 12 + 8);
        bh[0] = c0.x; bh[1] = c0.y; bh[2] = c0.z; bh[3] = c0.w;
        bh[4] = c1.x; bh[5] = c1.y; bh[6] = c1.z; bh[7] = c1.w;
        bh[8] = c2.x; bh[9] = c2.y; bh[10] = c2.z; bh[11] = c2.w;
    }
#pragma unroll
    for (int i = 0; i < 4; ++i) {
        int n = ntile + tr * 4 + i;
        if (n >= N_NODES) continue;
        float gg[12];
#pragma unroll
        for (int c = 0; c < 12; ++c) gg[c] = acc[1][i][c] + bh[c];
        float4 hv = *(const float4*)(H + (size_t)n * 64 + tc * 4);
        float res[4];
#pragma unroll
        for (int jj = 0; jj < 4; ++jj) {
            int c = jj * 3;
            float r = sigmoidf_(acc[0][i][c] + bb[c] + gg[c]);
            float z = sigmoidf_(acc[0][i][c + 1] + bb[c + 1] + gg[c + 1]);
            float nn = tanhf(acc[0][i][c + 2] + bb[c + 2] + r * gg[c + 2]);
            float hj = (jj == 0) ? hv.x : (jj == 1) ? hv.y : (jj == 2) ? hv.z : hv.w;
            res[jj] = (1.f - z) * nn + z * hj;
        }
        float4 o; o.x = res[0]; o.y = res[1]; o.z = res[2]; o.w = res[3];
        *(float4*)(H + (size_t)n * 64 + tc * 4) = o;
        if (do_trans) {
#pragma unroll
            for (int jj = 0; jj < 4; ++jj)
                sHT[(tc * 4 + jj) * 68 + (tr * 4 + i)] = res[jj];
        }
    }
    // trans tail: buf1 = h_new @ W256 + b256 (4 x 64-col chunks)
    if (do_trans) {
        __syncthreads();   // sHT complete; all phase readers of sW done
        int tc2 = tc * 4;
        for (int mt = 0; mt < 4; ++mt) {
            if (mt) __syncthreads();
#pragma unroll
            for (int i = 0; i < 4; ++i) {
                int idx = i * 256 + tid;            // 0..1023 float4s
                int row = idx >> 4, c4 = (idx & 15) * 4;
                *(float4*)(sW + row * 64 + c4) =
                    *(const float4*)(W256 + (size_t)row * 256 + mt * 64 + c4);
            }
            __syncthreads();
            float4 tacc[4];
#pragma unroll
            for (int i = 0; i < 4; ++i) tacc[i] = make_float4(0.f, 0.f, 0.f, 0.f);
            for (int kk = 0; kk < 64; kk += 2) {
                float4 wA = *(const float4*)(sW + kk * 64 + tc2);
                float4 wB = *(const float4*)(sW + (kk + 1) * 64 + tc2);
                float4 xA4 = *(const float4*)(sHT + kk * 68 + tr * 4);
                float4 xB4 = *(const float4*)(sHT + (kk + 1) * 68 + tr * 4);
                float xA[4] = {xA4.x, xA4.y, xA4.z, xA4.w};
                float xB[4] = {xB4.x, xB4.y, xB4.z, xB4.w};
#pragma unroll
                for (int i = 0; i < 4; ++i) {
                    tacc[i].x = fmaf(xA[i], wA.x, tacc[i].x);
                    tacc[i].y = fmaf(xA[i], wA.y, tacc[i].y);
                    tacc[i].z = fmaf(xA[i], wA.z, tacc[i].z);
                    tacc[i].w = fmaf(xA[i], wA.w, tacc[i].w);
                }
#pragma unroll
                for (int i = 0; i < 4; ++i) {
                    tacc[i].x = fmaf(xB[i], wB.x, tacc[i].x);
                    tacc[i].y = fmaf(xB[i], wB.y, tacc[i].y);
                    tacc[i].z = fmaf(xB[i], wB.z, tacc[i].z);
                    tacc[i].w = fmaf(xB[i], wB.w, tacc[i].w);
                }
            }
            float4 bv = *(const float4*)(b256 + mt * 64 + tc2);
#pragma unroll
            for (int i = 0; i < 4; ++i) {
                int n = ntile + tr * 4 + i;
                if (n < N_NODES) {
                    float4 y;
                    y.x = tacc[i].x + bv.x; y.y = tacc[i].y + bv.y;
                    y.z = tacc[i].z + bv.z; y.w = tacc[i].w + bv.w;
                    *(float4*)(buf1 + (size_t)n * 256 + mt * 64 + tc2) = y;
                }
            }
        }
    }
}

// ---------------- pooling: segmented, atomic-free, multi-block per graph ----------------
__global__ void k_bounds(const int* __restrict__ gid, int* __restrict__ start) {
    int n = blockIdx.x * 256 + threadIdx.x;
    if (n < N_NODES) {
        int g = gid[n];
        if (n == 0) {
            for (int x = 0; x <= g; ++x) start[x] = 0;
        } else {
            int pg = gid[n - 1];
            for (int x = pg + 1; x <= g; ++x) start[x] = n;
        }
        if (n == N_NODES - 1) {
            for (int x = g + 1; x <= NGRAPH; ++x) start[x] = N_NODES;
        }
    }
}

__global__ void k_gate2(const float* __restrict__ H, const float* __restrict__ H0,
                        const float* __restrict__ gW, const float* __restrict__ gb,
                        float* __restrict__ gate) {
    int l = threadIdx.x & 63;
    int n = blockIdx.x * 4 + (threadIdx.x >> 6);
    float v = H[(size_t)n * 64 + l] * gW[l] + H0[(size_t)n * 64 + l] * gW[64 + l];
    for (int off = 32; off > 0; off >>= 1) v += __shfl_xor(v, off, 64);
    if (l == 0) gate[n] = v + gb[0];
}

__global__ __launch_bounds__(64) void k_poolA(const float* __restrict__ gate,
                                              const int* __restrict__ start,
                                              float* __restrict__ pmax) {
    int g = blockIdx.x, s = blockIdx.y;
    int beg = start[g], len = start[g + 1] - beg;
    int sb = beg + (int)((long long)len * s / PS);
    int se = beg + (int)((long long)len * (s + 1) / PS);
    float m = -INFINITY;
    for (int n = sb + threadIdx.x; n < se; n += 64) m = fmaxf(m, gate[n]);
    for (int off = 32; off > 0; off >>= 1) m = fmaxf(m, __shfl_xor(m, off, 64));
    if (threadIdx.x == 0) pmax[g * PS + s] = m;
}

__global__ void k_poolB(const float* __restrict__ pmax, float* __restrict__ gm) {
    int g = threadIdx.x;  // 64 threads
    float m = -INFINITY;
    for (int s = 0; s < PS; ++s) m = fmaxf(m, pmax[g * PS + s]);
    if (!isfinite(m)) m = 0.0f;   // reference's empty-graph guard
    gm[g] = m;
}

__global__ __launch_bounds__(256) void k_poolC(const float* __restrict__ H,
                                               const float* __restrict__ H0,
                                               const float* __restrict__ gate,
                                               const int* __restrict__ start,
                                               const float* __restrict__ gm,
                                               float* __restrict__ pnum,
                                               float* __restrict__ pden) {
    int g = blockIdx.x, s = blockIdx.y;
    int beg = start[g], len = start[g + 1] - beg;
    int sb = beg + (int)((long long)len * s / PS);
    int se = beg + (int)((long long)len * (s + 1) / PS);
    int t = threadIdx.x;
    int lane = t & 63, wave = t >> 6;
    float m = gm[g];
    __shared__ float shh[4][64], sh0[4][64], ses[4];
    float ah = 0.f, ah0 = 0.f, es = 0.f;
    for (int n = sb + wave; n < se; n += 4) {
        float e = expf(gate[n] - m);
        es += e;
        ah  += e * H [(size_t)n * 64 + lane];
        ah0 += e * H0[(size_t)n * 64 + lane];
    }
    shh[wave][lane] = ah; sh0[wave][lane] = ah0;
    if (lane == 0) ses[wave] = es;
    __syncthreads();
    if (wave == 0) {
        float r  = shh[0][lane] + shh[1][lane] + shh[2][lane] + shh[3][lane];
        float r0 = sh0[0][lane] + sh0[1][lane] + sh0[2][lane] + sh0[3][lane];
        int base = (g * PS + s) * 128;
        pnum[base + lane]      = r;
        pnum[base + 64 + lane] = r0;
        if (lane == 0) pden[g * PS + s] = ses[0] + ses[1] + ses[2] + ses[3];
    }
}

__global__ __launch_bounds__(128) void k_poolD(const float* __restrict__ pnum,
                                               const float* __restrict__ pden,
                                               float* __restrict__ ro) {
    int g = blockIdx.x;
    int c = threadIdx.x;
    float den = 0.f;
    for (int s = 0; s < PS; ++s) den += pden[g * PS + s];
    float nu = 0.f;
    for (int s = 0; s < PS; ++s) nu += pnum[(g * PS + s) * 128 + c];
    ro[g * 128 + c] = (den > 0.f) ? nu / den : 0.f;
}

__global__ void k_logits(const float* __restrict__ ro, const float* __restrict__ oW,
                         const float* __restrict__ ob, float* __restrict__ out) {
    int t = threadIdx.x;
    int b = t >> 1;
    int c = t & 1;
    float acc = ob[c];
    for (int k = 0; k < 128; ++k) acc = fmaf(ro[b * 128 + k], oW[k * 2 + c], acc);
    out[b * 2 + c] = acc;
}

extern "C" void kernel_launch(void* const* d_in, const int* in_sizes, int n_in,
                              void* d_out, int out_size, void* d_ws, size_t ws_size,
                              hipStream_t stream) {
    (void)in_sizes; (void)n_in; (void)out_size; (void)ws_size;
    const float* ann = (const float*)d_in[0];
    const int* src   = (const int*)d_in[1];
    const int* dst   = (const int*)d_in[2];
    const int* ety   = (const int*)d_in[3];
    const int* gid   = (const int*)d_in[4];
    const float* rW  = (const float*)d_in[5];
    const float* rb  = (const float*)d_in[6];
    const float* eW  = (const float*)d_in[7];
    const float* eb  = (const float*)d_in[8];
    const float* Wi  = (const float*)d_in[9];
    const float* Bi  = (const float*)d_in[10];
    const float* Wh  = (const float*)d_in[11];
    const float* Bh  = (const float*)d_in[12];
    const float* gW  = (const float*)d_in[13];
    const float* gb  = (const float*)d_in[14];
    const float* oW  = (const float*)d_in[15];
    const float* ob  = (const float*)d_in[16];
    float* out = (float*)d_out;

    char* p = (char*)d_ws;
    auto take = [&](size_t nbytes) -> void* {
        void* r = (void*)p;
        p += (nbytes + 255) & ~((size_t)255);
        return r;
    };
    float* h0      = (float*)take((size_t)N_NODES * 64 * 4);
    float* h       = (float*)take((size_t)N_NODES * 64 * 4);
    float* abuf    = (float*)take((size_t)N_NODES * 64 * 4);
    float* buf1    = (float*)take((size_t)N_NODES * 256 * 4);   // trans only [N][4*64]
    float* W256    = (float*)take(64 * 256 * 4);
    float* b256    = (float*)take(256 * 4);
    float* Wh192   = (float*)take(64 * 192 * 4);
    float* bh192   = (float*)take(192 * 4);
    float* WiA     = (float*)take(64 * 192 * 4);
    float* biA     = (float*)take(192 * 4);
    int* deg       = (int*)take((size_t)N_NODES * 4);
    int* cur       = (int*)take((size_t)N_NODES * 4);
    int* rs        = (int*)take((size_t)(N_NODES + 1) * 4);
    int* part      = (int*)take(512);
    int* colidx    = (int*)take((size_t)N_EDGES * 4);
    float* gate    = (float*)take((size_t)N_NODES * 4);
    int* start     = (int*)take((size_t)(NGRAPH + 1) * 4);
    float* pmax    = (float*)take(NGRAPH * PS * 4);
    float* gm      = (float*)take(NGRAPH * 4);
    float* pnum    = (float*)take((size_t)NGRAPH * PS * 128 * 4);
    float* pden    = (float*)take(NGRAPH * PS * 4);
    float* ro      = (float*)take(NGRAPH * 128 * 4);

    // ---- CSR build (by dst)
    hipMemsetAsync(deg, 0, (size_t)N_NODES * 4, stream);
    hipMemsetAsync(cur, 0, (size_t)N_NODES * 4, stream);
    k_count<<<(N_EDGES + 255) / 256, 256, 0, stream>>>(dst, deg);
    int nb = (N_NODES + 1023) / 1024;  // 98
    k_scan1<<<nb, 256, 0, stream>>>(deg, rs, part);
    k_scan2<<<1, 64, 0, stream>>>(part, rs, nb);
    k_scan3<<<(N_NODES + 255) / 256, 256, 0, stream>>>(rs, part);
    k_fill<<<(N_EDGES + 255) / 256, 256, 0, stream>>>(src, dst, ety, rs, cur, colidx);

    // ---- weight prep + graph bounds
    k_prep2<<<112, 256, 0, stream>>>(Wh, Bh, eW, eb, Wi, Bi, W256, b256, Wh192, bh192, WiA, biA);
    k_bounds<<<(N_NODES + 255) / 256, 256, 0, stream>>>(gid, start);

    int ntiles = (N_NODES + 127) / 128;  // 782

    // ---- reduce layer: h = h0 = ann @ rW + rb (K-pipelined)
    k_gemm_red<<<ntiles, 256, 0, stream>>>(ann, rW, rb, h, h0);

    // ---- pre-loop trans of h0 into buf1
    k_gemm<<<dim3(4, ntiles), 256, 0, stream>>>(h, 64, 64, W256, 256, b256,
                                                buf1, nullptr, 256);

    // ---- message-passing steps: aggregate + fused GRU/trans (trans skipped on last step)
    for (int s = 0; s < NSTEPS; ++s) {
        k_aggregate<<<N_NODES / 4, 256, 0, stream>>>(buf1, rs, colidx, abuf);
        k_gruF3<<<(N_NODES + 63) / 64, 256, 0, stream>>>(abuf, WiA, biA, Wh192, bh192,
                                                         W256, b256, h, buf1,
                                                         (s < NSTEPS - 1) ? 1 : 0);
    }

    // ---- pooling + classifier (atomic-free, multi-block)
    k_gate2<<<N_NODES / 4, 256, 0, stream>>>(h, h0, gW, gb, gate);
    k_poolA<<<dim3(NGRAPH, PS), 64, 0, stream>>>(gate, start, pmax);
    k_poolB<<<1, 64, 0, stream>>>(pmax, gm);
    k_poolC<<<dim3(NGRAPH, PS), 256, 0, stream>>>(h, h0, gate, start, gm, pnum, pden);
    k_poolD<<<NGRAPH, 128, 0, stream>>>(pnum, pden, ro);
    k_logits<<<1, 128, 0, stream>>>(ro, oW, ob, out);
}